// Round 14
// baseline (1388.152 us; speedup 1.0000x reference)
//
#include <hip/hip_runtime.h>
#include <hip/hip_bf16.h>
#include <math.h>

// Problem dims (fixed)
#define BB 2
#define LL 1024
#define DM 768
#define NL 8
#define DS 16
#define DC 4
#define DI 1536
#define DTR 48
#define NTOK (BB*LL)          // 2048
#define WXROWS (DTR + 2*DS)   // 80
#define NC 64                 // scan chunks
#define CT (LL/NC)            // 16 timesteps per chunk
#define SKS 8                 // split-K for W_x GEMM
#define SKC (DI/SKS)          // 192 per split
#define SK4 3                 // split-K for W_out GEMM
#define SK4C (DI/SK4)         // 512 per split
#define DTB 8                 // tokens per delta-kernel block

typedef __attribute__((ext_vector_type(8))) short bf16x8;
typedef __attribute__((ext_vector_type(4))) float f32x4;

__device__ inline void gload_lds16(const void* g, void* l) {
    __builtin_amdgcn_global_load_lds(
        (const __attribute__((address_space(1))) unsigned int*)g,
        (__attribute__((address_space(3))) unsigned int*)l, 16, 0, 0);
}

// bijective XCD swizzle for nwg % 8 == 0
__device__ inline int xcd_swz(int orig, int nwg) {
    return (orig & 7) * (nwg >> 3) + (orig >> 3);
}

// ---------------- MFMA core: 64(M) x 128(N) tile, BK=32, single buffer ----------------
// (R12-proven: stage -> vmcnt(0) -> barrier -> MFMA -> barrier; R13's 2-phase was null-negative)
__device__ inline void gemm_core64(
    const __hip_bfloat16* __restrict__ gA0,
    const __hip_bfloat16* __restrict__ gW0, const __hip_bfloat16* __restrict__ gW1,
    int kbeg, int kend, int w, int wr, int wc, int fr, int khi,
    f32x4 (&acc)[2][4])
{
    __shared__ short As[2048];
    __shared__ short Ws[4096];
    short* AsW = As + w * 512;
    short* WsW = Ws + w * 512;
    for (int k0 = kbeg; k0 < kend; k0 += 32) {
        gload_lds16(gA0 + k0, AsW);
        gload_lds16(gW0 + k0, WsW);
        gload_lds16(gW1 + k0, WsW + 2048);
        asm volatile("s_waitcnt vmcnt(0)" ::: "memory");
        __syncthreads();
        bf16x8 a4[2], b4[4];
        #pragma unroll
        for (int mi = 0; mi < 2; ++mi)
            a4[mi] = *(const bf16x8*)&As[(wr*32 + mi*16 + fr)*32 + khi*8];
        #pragma unroll
        for (int ni = 0; ni < 4; ++ni)
            b4[ni] = *(const bf16x8*)&Ws[(wc*64 + ni*16 + fr)*32 + khi*8];
        #pragma unroll
        for (int mi = 0; mi < 2; ++mi)
            #pragma unroll
            for (int ni = 0; ni < 4; ++ni)
                acc[mi][ni] = __builtin_amdgcn_mfma_f32_16x16x32_bf16(
                    a4[mi], b4[ni], acc[mi][ni], 0, 0, 0);
        __syncthreads();
    }
}

// ---------------- tiled input transpose: batch[b,d,l] -> h[b,l,d] ----------------
__global__ __launch_bounds__(256) void transpose_in_kernel(
    const float* __restrict__ batch, float* __restrict__ h)
{
    __shared__ float tile[32][33];
    const int b  = blockIdx.z;
    const int l0 = blockIdx.x * 32;
    const int d0 = blockIdx.y * 32;
    const int tx = threadIdx.x & 31;
    const int ty = threadIdx.x >> 5;          // 0..7
    #pragma unroll
    for (int i = ty; i < 32; i += 8)
        tile[i][tx] = batch[((size_t)b*DM + d0 + i)*LL + l0 + tx];
    __syncthreads();
    #pragma unroll
    for (int i = ty; i < 32; i += 8)
        h[((size_t)b*LL + l0 + i)*DM + d0 + tx] = tile[tx][i];
}

// ---------------- lengths from mask (robust to bool vs int32) ----------------
__global__ void lengths_kernel(const void* __restrict__ mask, int* __restrict__ lengths)
{
    int b = threadIdx.x;
    if (b >= BB) return;
    const unsigned int* mi = (const unsigned int*)mask;
    bool packed = (mi[0] == 0x01010101u);
    int cnt = 0;
    if (packed) {
        const unsigned char* mb = (const unsigned char*)mask;
        for (int i = 0; i < LL; ++i) cnt += (mb[(size_t)b*LL + i] != 0);
    } else {
        for (int i = 0; i < LL; ++i) cnt += (mi[(size_t)b*LL + i] != 0);
    }
    lengths[b] = cnt;
}

// ---------------- f32 -> bf16 conversions ----------------
__global__ __launch_bounds__(256) void cvt_bf16_kernel(
    const float* __restrict__ in, __hip_bfloat16* __restrict__ o, int n)
{
    int i = (blockIdx.x * 256 + threadIdx.x) * 4;
    if (i >= n) return;
    float4 v = *(const float4*)(in + i);
    __hip_bfloat16 h0 = __float2bfloat16(v.x);
    __hip_bfloat16 h1 = __float2bfloat16(v.y);
    __hip_bfloat16 h2 = __float2bfloat16(v.z);
    __hip_bfloat16 h3 = __float2bfloat16(v.w);
    ushort4 r;
    r.x = *(unsigned short*)&h0; r.y = *(unsigned short*)&h1;
    r.z = *(unsigned short*)&h2; r.w = *(unsigned short*)&h3;
    *(ushort4*)(o + i) = r;
}

__global__ __launch_bounds__(256) void cvt_padrow_kernel(
    const float* __restrict__ in, __hip_bfloat16* __restrict__ o,
    int nrin, int nrout, int ncol, int nmat)
{
    int i = (blockIdx.x * 256 + threadIdx.x) * 4;
    int tot = nmat * nrout * ncol;
    if (i >= tot) return;
    int m = i / (nrout * ncol);
    int rem = i - m * (nrout * ncol);
    int r = rem / ncol;
    int c = rem - r * ncol;
    ushort4 rr = {0,0,0,0};
    if (r < nrin) {
        float4 v = *(const float4*)(in + ((size_t)m*nrin + r)*ncol + c);
        __hip_bfloat16 h0 = __float2bfloat16(v.x);
        __hip_bfloat16 h1 = __float2bfloat16(v.y);
        __hip_bfloat16 h2 = __float2bfloat16(v.z);
        __hip_bfloat16 h3 = __float2bfloat16(v.w);
        rr.x = *(unsigned short*)&h0; rr.y = *(unsigned short*)&h1;
        rr.z = *(unsigned short*)&h2; rr.w = *(unsigned short*)&h3;
    }
    *(ushort4*)(o + i) = rr;
}

// ---------------- RMSNorm (per token, D=768) -> bf16 out ----------------
__global__ __launch_bounds__(256) void rmsnorm_kernel(
    const float* __restrict__ x, const float* __restrict__ w,
    __hip_bfloat16* __restrict__ o)
{
    int tok = blockIdx.x;
    const float* xr = x + (size_t)tok * DM;
    float ss = 0.f;
    for (int j = threadIdx.x; j < DM; j += 256) { float v = xr[j]; ss += v*v; }
    #pragma unroll
    for (int off = 32; off > 0; off >>= 1) ss += __shfl_down(ss, off);
    __shared__ float red[4];
    int lane = threadIdx.x & 63, wv = threadIdx.x >> 6;
    if (lane == 0) red[wv] = ss;
    __syncthreads();
    if (threadIdx.x == 0) {
        float t = red[0] + red[1] + red[2] + red[3];
        red[0] = rsqrtf(t / (float)DM + 1e-5f);
    }
    __syncthreads();
    float r = red[0];
    for (int j = threadIdx.x; j < DM; j += 256)
        o[(size_t)tok*DM + j] = __float2bfloat16(xr[j] * w[j] * r);
}

// ---------------- MFMA bf16 GEMM (full K, 64M x 128N tiles, swizzled): C = A @ W^T ----------------
__global__ __launch_bounds__(256) void gemm_mfma_kernel(
    const __hip_bfloat16* __restrict__ A,
    const __hip_bfloat16* __restrict__ W,
    __hip_bfloat16* __restrict__ C,
    int NT, int M, int N, int K)
{
    const int swz = xcd_swz(blockIdx.x, gridDim.x);
    const int bn = (swz % NT) * 128;
    const int bm = (swz / NT) * 64;
    const int t = threadIdx.x;
    const int w = t >> 6;
    const int lane = t & 63;
    const int wr = w >> 1, wc = w & 1;
    const int fr = lane & 15;
    const int khi = lane >> 4;

    f32x4 acc[2][4];
    #pragma unroll
    for (int mi = 0; mi < 2; ++mi)
        #pragma unroll
        for (int ni = 0; ni < 4; ++ni)
            acc[mi][ni] = (f32x4){0.f, 0.f, 0.f, 0.f};

    const int rowL = t >> 2;
    const int ks = (t & 3) * 8;
    gemm_core64(A + (size_t)(bm + rowL) * K + ks,
                W + (size_t)(bn + rowL) * K + ks,
                W + (size_t)(bn + 64 + rowL) * K + ks,
                0, K, w, wr, wc, fr, khi, acc);

    #pragma unroll
    for (int mi = 0; mi < 2; ++mi) {
        #pragma unroll
        for (int ni = 0; ni < 4; ++ni) {
            int gc = bn + wc*64 + ni*16 + fr;
            #pragma unroll
            for (int r = 0; r < 4; ++r) {
                int gr = bm + wr*32 + mi*16 + khi*4 + r;
                C[(size_t)gr * N + gc] = __float2bfloat16(acc[mi][ni][r]);
            }
        }
    }
}

// ---------------- W_out GEMM split-K=3, 64M tiles, swizzled 1D grid (576 blocks) ----------------
__global__ __launch_bounds__(256) void gemm_mfma_splitk4(
    const __hip_bfloat16* __restrict__ A,
    const __hip_bfloat16* __restrict__ W,
    float* __restrict__ Cp)
{
    const int swz = xcd_swz(blockIdx.x, gridDim.x);
    const int bm = (swz / 18) * 64;
    const int r18 = swz % 18;
    const int bn = (r18 % 6) * 128;
    const int split = r18 / 6;
    const int t = threadIdx.x;
    const int w = t >> 6;
    const int lane = t & 63;
    const int wr = w >> 1, wc = w & 1;
    const int fr = lane & 15;
    const int khi = lane >> 4;

    f32x4 acc[2][4];
    #pragma unroll
    for (int mi = 0; mi < 2; ++mi)
        #pragma unroll
        for (int ni = 0; ni < 4; ++ni)
            acc[mi][ni] = (f32x4){0.f, 0.f, 0.f, 0.f};

    const int rowL = t >> 2;
    const int ks = (t & 3) * 8;
    const int kbeg = split * SK4C;
    gemm_core64(A + (size_t)(bm + rowL) * DI + ks,
                W + (size_t)(bn + rowL) * DI + ks,
                W + (size_t)(bn + 64 + rowL) * DI + ks,
                kbeg, kbeg + SK4C, w, wr, wc, fr, khi, acc);

    #pragma unroll
    for (int mi = 0; mi < 2; ++mi) {
        #pragma unroll
        for (int ni = 0; ni < 4; ++ni) {
            int gc = bn + wc*64 + ni*16 + fr;
            #pragma unroll
            for (int r = 0; r < 4; ++r) {
                int gr = bm + wr*32 + mi*16 + khi*4 + r;
                Cp[((size_t)split*NTOK + gr)*DM + gc] = acc[mi][ni][r];
            }
        }
    }
}

// reduce split-K partials + residual add + next-layer RMSNorm (fused)
__global__ __launch_bounds__(256) void reduce_add_norm_kernel(
    const float* __restrict__ Cp, float* __restrict__ h,
    const float* __restrict__ nw, __hip_bfloat16* __restrict__ xn)
{
    int tok = blockIdx.x;
    int tid = threadIdx.x;
    float v[3];
    float ss = 0.f;
    #pragma unroll
    for (int r = 0; r < 3; ++r) {
        int j = tid + r*256;
        size_t o = (size_t)tok*DM + j;
        float x = h[o] + Cp[o] + Cp[(size_t)NTOK*DM + o] + Cp[2*(size_t)NTOK*DM + o];
        h[o] = x;
        v[r] = x;
        ss += x*x;
    }
    if (!nw) return;
    #pragma unroll
    for (int off = 32; off > 0; off >>= 1) ss += __shfl_down(ss, off);
    __shared__ float red[4];
    int lane = tid & 63, wv = tid >> 6;
    if (lane == 0) red[wv] = ss;
    __syncthreads();
    if (tid == 0) {
        float t = red[0] + red[1] + red[2] + red[3];
        red[0] = rsqrtf(t / (float)DM + 1e-5f);
    }
    __syncthreads();
    float rinv = red[0];
    #pragma unroll
    for (int r = 0; r < 3; ++r) {
        int j = tid + r*256;
        xn[(size_t)tok*DM + j] = __float2bfloat16(v[r] * nw[j] * rinv);
    }
}

// ---------------- skinny MFMA split-K GEMM (64M tiles): dblp[split][m][0..79] ----------------
__global__ __launch_bounds__(256) void gemm_mfma_skinny(
    const __hip_bfloat16* __restrict__ A,
    const __hip_bfloat16* __restrict__ W,
    float* __restrict__ Cp)
{
    const int split = blockIdx.x;
    const int bm = blockIdx.y * 64;
    const int t = threadIdx.x;
    const int w = t >> 6;
    const int lane = t & 63;
    const int wr = w >> 1, wc = w & 1;
    const int fr = lane & 15;
    const int khi = lane >> 4;

    f32x4 acc[2][4];
    #pragma unroll
    for (int mi = 0; mi < 2; ++mi)
        #pragma unroll
        for (int ni = 0; ni < 4; ++ni)
            acc[mi][ni] = (f32x4){0.f, 0.f, 0.f, 0.f};

    const int rowL = t >> 2;
    const int ks = (t & 3) * 8;
    const int kbeg = split * SKC;
    gemm_core64(A + (size_t)(bm + rowL) * DI + ks,
                W + (size_t)rowL * DI + ks,
                W + (size_t)(64 + rowL) * DI + ks,
                kbeg, kbeg + SKC, w, wr, wc, fr, khi, acc);

    #pragma unroll
    for (int mi = 0; mi < 2; ++mi) {
        #pragma unroll
        for (int ni = 0; ni < 4; ++ni) {
            int gc = wc*64 + ni*16 + fr;
            if (gc >= WXROWS) continue;
            #pragma unroll
            for (int r = 0; r < 4; ++r) {
                int gr = bm + wr*32 + mi*16 + khi*4 + r;
                Cp[((size_t)split*NTOK + gr)*WXROWS + gc] = acc[mi][ni][r];
            }
        }
    }
}

// ---------------- fused split-K reduce + delta ----------------
__global__ __launch_bounds__(256) void reduce_delta_kernel(
    const float* __restrict__ Cp,
    const float* __restrict__ W_dt, const float* __restrict__ b_dt,
    float* __restrict__ dbl, __hip_bfloat16* __restrict__ delta)
{
    __shared__ float ld[DTB*DTR];
    const int tid = threadIdx.x;
    const int d = blockIdx.x * 256 + tid;
    const int t0 = blockIdx.y * DTB;
    for (int j = tid; j < DTB*DTR; j += 256) {
        int tt = j / DTR, jj = j - tt*DTR;
        float s = 0.f;
        #pragma unroll
        for (int p = 0; p < SKS; ++p)
            s += Cp[((size_t)p*NTOK + t0 + tt)*WXROWS + jj];
        ld[j] = s;
    }
    if (blockIdx.x == 0) {
        for (int j = tid; j < DTB*WXROWS; j += 256) {
            int tt = j / WXROWS, jj = j - tt*WXROWS;
            float s = 0.f;
            #pragma unroll
            for (int p = 0; p < SKS; ++p)
                s += Cp[((size_t)p*NTOK + t0 + tt)*WXROWS + jj];
            dbl[(size_t)(t0 + tt)*WXROWS + jj] = s;
        }
    }
    float wdt[DTR];
    #pragma unroll
    for (int j = 0; j < DTR; j += 4) {
        float4 v = *(const float4*)(W_dt + (size_t)d*DTR + j);
        wdt[j] = v.x; wdt[j+1] = v.y; wdt[j+2] = v.z; wdt[j+3] = v.w;
    }
    const float bdt = b_dt[d];
    __syncthreads();
    #pragma unroll
    for (int tt = 0; tt < DTB; ++tt) {
        float dt = bdt;
        #pragma unroll
        for (int j = 0; j < DTR; ++j) dt = fmaf(ld[tt*DTR + j], wdt[j], dt);
        dt = (dt > 20.f) ? dt : log1pf(__expf(dt));
        delta[(size_t)(t0 + tt)*DI + d] = __float2bfloat16(dt);
    }
}

// ---------------- vectorized causal depthwise conv4 + bias + SiLU (8 ch/thread) ----------------
__global__ __launch_bounds__(256) void conv_silu_kernel(
    const __hip_bfloat16* __restrict__ xz, const float* __restrict__ cw,
    const float* __restrict__ cb, __hip_bfloat16* __restrict__ u)
{
    int idx = blockIdx.x * 256 + threadIdx.x;      // NTOK*DI/8 threads
    if (idx >= NTOK*DI/8) return;
    const int dg  = idx % (DI/8);
    const int row = idx / (DI/8);                   // b*LL + l
    const int l   = row % LL;
    const int d0  = dg * 8;

    float acc[8];
    {
        float4 c0 = *(const float4*)(cb + d0);
        float4 c1 = *(const float4*)(cb + d0 + 4);
        acc[0]=c0.x; acc[1]=c0.y; acc[2]=c0.z; acc[3]=c0.w;
        acc[4]=c1.x; acc[5]=c1.y; acc[6]=c1.z; acc[7]=c1.w;
    }
    float4 cwj[8];
    #pragma unroll
    for (int j = 0; j < 8; ++j)
        cwj[j] = *(const float4*)(cw + (size_t)(d0 + j)*4);

    #pragma unroll
    for (int k = 0; k < 4; ++k) {
        int ls = l - 3 + k;
        if (ls < 0) continue;
        bf16x8 v = *(const bf16x8*)(xz + (size_t)(row - 3 + k)*(2*DI) + d0);
        const __hip_bfloat16* vp = (const __hip_bfloat16*)&v;
        #pragma unroll
        for (int j = 0; j < 8; ++j) {
            float xv = __bfloat162float(vp[j]);
            float wv = (k == 0) ? cwj[j].x : (k == 1) ? cwj[j].y : (k == 2) ? cwj[j].z : cwj[j].w;
            acc[j] = fmaf(xv, wv, acc[j]);
        }
    }
    bf16x8 r;
    __hip_bfloat16* rp = (__hip_bfloat16*)&r;
    #pragma unroll
    for (int j = 0; j < 8; ++j) {
        float s = acc[j] / (1.f + __expf(-acc[j]));
        rp[j] = __float2bfloat16(s);
    }
    *(bf16x8*)(u + (size_t)row*DI + d0) = r;
}

// ================= chunk-parallel selective scan (delta precomputed bf16, NC=64) =================
__global__ __launch_bounds__(256) void scan_phaseA(
    const __hip_bfloat16* __restrict__ delta, const __hip_bfloat16* __restrict__ u,
    const float* __restrict__ dbl, const float* __restrict__ A_log,
    float* __restrict__ Psum, float* __restrict__ Hsum)
{
    const int d = blockIdx.x * 256 + threadIdx.x;
    const int c = blockIdx.y;
    const int b = blockIdx.z;
    float A[DS], P[DS], hl[DS];
    #pragma unroll
    for (int s = 0; s < DS; ++s) {
        A[s] = -expf(A_log[(size_t)d*DS + s]);
        P[s] = 1.f; hl[s] = 0.f;
    }
    const int t0 = c * CT;
    for (int t = t0; t < t0 + CT; ++t) {
        const size_t row = (size_t)b*LL + t;
        const float* bc = dbl + row*WXROWS + DTR;
        float dt = __bfloat162float(delta[row*DI + d]);
        float du = dt * __bfloat162float(u[row*DI + d]);
        #pragma unroll
        for (int s = 0; s < DS; ++s) {
            float a = __expf(dt * A[s]);
            P[s] *= a;
            hl[s] = fmaf(a, hl[s], du * bc[s]);
        }
    }
    const size_t off = (((size_t)b*NC + c)*DI + d)*DS;
    #pragma unroll
    for (int s = 0; s < DS; ++s) { Psum[off+s] = P[s]; Hsum[off+s] = hl[s]; }
}

// wave-parallel phaseB: one wave per (b, d*DS+s) row; lane = chunk index.
// 6-step shfl_up composition replaces the 64-iteration serial global chain.
__global__ __launch_bounds__(256) void scan_phaseB(
    const float* __restrict__ Psum, const float* __restrict__ Hsum,
    float* __restrict__ Hin)
{
    const int wid = (blockIdx.x * 256 + threadIdx.x) >> 6;   // global wave id
    const int lane = threadIdx.x & 63;                        // chunk c (NC=64)
    if (wid >= BB*DI*DS) return;
    const int b = wid / (DI*DS);
    const int r = wid % (DI*DS);
    const size_t off = ((size_t)(b*NC + lane))*DI*DS + r;
    float P  = Psum[off];
    float hl = Hsum[off];
    // inclusive scan over lanes: (P,h) composed with prefix (P',h'): h = P*h' + h; P = P*P'
    #pragma unroll
    for (int o = 1; o < 64; o <<= 1) {
        float Pp = __shfl_up(P, o);
        float hp = __shfl_up(hl, o);
        if (lane >= o) {
            hl = fmaf(P, hp, hl);
            P *= Pp;
        }
    }
    // exclusive shift -> carry-in for chunk c
    float hin = __shfl_up(hl, 1);
    Hin[off] = (lane == 0) ? 0.f : hin;
}

__global__ __launch_bounds__(256) void scan_phaseC(
    const __hip_bfloat16* __restrict__ delta, const __hip_bfloat16* __restrict__ u,
    const float* __restrict__ dbl, const __hip_bfloat16* __restrict__ xz,
    const float* __restrict__ A_log, const float* __restrict__ Dsk,
    const float* __restrict__ Hin, __hip_bfloat16* __restrict__ yfull)
{
    const int d = blockIdx.x * 256 + threadIdx.x;
    const int c = blockIdx.y;
    const int b = blockIdx.z;
    float A[DS], h[DS];
    const size_t hoff = (((size_t)b*NC + c)*DI + d)*DS;
    #pragma unroll
    for (int s = 0; s < DS; ++s) {
        A[s] = -expf(A_log[(size_t)d*DS + s]);
        h[s] = Hin[hoff + s];
    }
    const float dsk = Dsk[d];
    const int t0 = c * CT;
    for (int t = t0; t < t0 + CT; ++t) {
        const size_t row = (size_t)b*LL + t;
        const float* bc = dbl + row*WXROWS + DTR;
        float dt = __bfloat162float(delta[row*DI + d]);
        float ut = __bfloat162float(u[row*DI + d]);
        float du = dt * ut;
        float y = 0.f;
        #pragma unroll
        for (int s = 0; s < DS; ++s) {
            float a = __expf(dt * A[s]);
            h[s] = fmaf(a, h[s], du * bc[s]);
            y = fmaf(h[s], bc[DS+s], y);
        }
        float zt = __bfloat162float(xz[row*(2*DI) + DI + d]);
        float sz = zt / (1.f + __expf(-zt));
        yfull[row*DI + d] = __float2bfloat16((y + ut * dsk) * sz);
    }
}

// ---------------- final rmsnorm + gather last valid token ----------------
__global__ __launch_bounds__(256) void final_kernel(
    const float* __restrict__ h, const float* __restrict__ w,
    const int* __restrict__ lengths, float* __restrict__ out)
{
    int b = blockIdx.x;
    int idx = lengths[b] - 1;
    const float* xr = h + ((size_t)b*LL + idx)*DM;
    float ss = 0.f;
    for (int j = threadIdx.x; j < DM; j += 256) { float v = xr[j]; ss += v*v; }
    #pragma unroll
    for (int off = 32; off > 0; off >>= 1) ss += __shfl_down(ss, off);
    __shared__ float red[4];
    int lane = threadIdx.x & 63, wv = threadIdx.x >> 6;
    if (lane == 0) red[wv] = ss;
    __syncthreads();
    if (threadIdx.x == 0) {
        float t = red[0] + red[1] + red[2] + red[3];
        red[0] = rsqrtf(t / (float)DM + 1e-5f);
    }
    __syncthreads();
    float r = red[0];
    for (int j = threadIdx.x; j < DM; j += 256)
        out[(size_t)b*DM + j] = xr[j] * w[j] * r;
}

extern "C" void kernel_launch(void* const* d_in, const int* in_sizes, int n_in,
                              void* d_out, int out_size, void* d_ws, size_t ws_size,
                              hipStream_t stream)
{
    const float* batch   = (const float*)d_in[0];
    const void*  mask    = d_in[1];
    const float* norm_w  = (const float*)d_in[2];
    const float* W_in    = (const float*)d_in[3];
    const float* conv_w  = (const float*)d_in[4];
    const float* conv_b  = (const float*)d_in[5];
    const float* W_x     = (const float*)d_in[6];
    const float* W_dt    = (const float*)d_in[7];
    const float* b_dt    = (const float*)d_in[8];
    const float* A_log   = (const float*)d_in[9];
    const float* D_skip  = (const float*)d_in[10];
    const float* W_out   = (const float*)d_in[11];
    const float* normf_w = (const float*)d_in[12];
    float* out = (float*)d_out;

    // ---------------- workspace layout ----------------
    float* ws   = (float*)d_ws;
    float* h    = ws;                            // NTOK*DM f32
    float* dbl  = h   + (size_t)NTOK*DM;         // NTOK*80 f32
    float* scr  = dbl + (size_t)NTOK*WXROWS;     // 3*SEG f32 (aliased scratch)
    const size_t SEG = (size_t)BB*NC*DI*DS;      // 3,145,728 (NC=64)
    float* dblp = scr;                           // [SKS][NTOK][80]
    float* Psum = scr;
    float* Hsum = scr + SEG;
    float* Hin  = scr + 2*SEG;
    float* Cp4  = scr;                           // [SK4][NTOK][DM]
    __hip_bfloat16* xz_bf    = (__hip_bfloat16*)(scr + 3*SEG);
    __hip_bfloat16* xn_bf    = xz_bf + (size_t)NTOK*2*DI;
    __hip_bfloat16* u_bf     = xn_bf + (size_t)NTOK*DM;
    __hip_bfloat16* delta_bf = u_bf  + (size_t)NTOK*DI;
    __hip_bfloat16* y_bf     = delta_bf + (size_t)NTOK*DI;
    __hip_bfloat16* wbase    = y_bf + (size_t)NTOK*DI;

    const size_t WIN_L  = (size_t)2*DI*DM;
    const size_t WOUT_L = (size_t)DM*DI;
    const size_t WXP_L  = (size_t)128*DI;
    const size_t WSUM   = WIN_L + WOUT_L + WXP_L;

    size_t need_all = (size_t)((char*)(wbase + (size_t)NL*WSUM) - (char*)d_ws) + 256;
    const bool all = ws_size >= need_all;
    const int nlw = all ? NL : 1;

    __hip_bfloat16* Win_b  = wbase;
    __hip_bfloat16* Wout_b = Win_b  + (size_t)nlw*WIN_L;
    __hip_bfloat16* Wxp_b  = Wout_b + (size_t)nlw*WOUT_L;
    int* lengths = (int*)(Wxp_b + (size_t)nlw*WXP_L);

    transpose_in_kernel<<<dim3(LL/32, DM/32, BB), 256, 0, stream>>>(batch, h);
    lengths_kernel<<<1, 64, 0, stream>>>(mask, lengths);

    if (all) {
        cvt_bf16_kernel<<<(int)(NL*WIN_L/4/256), 256, 0, stream>>>(W_in, Win_b, (int)(NL*WIN_L));
        cvt_bf16_kernel<<<(int)(NL*WOUT_L/4/256), 256, 0, stream>>>(W_out, Wout_b, (int)(NL*WOUT_L));
        cvt_padrow_kernel<<<(int)(NL*WXP_L/4/256), 256, 0, stream>>>(
            W_x, Wxp_b, WXROWS, 128, DI, NL);
    }

    // layer-0 pre-norm
    rmsnorm_kernel<<<NTOK, 256, 0, stream>>>(h, norm_w, xn_bf);

    for (int i = 0; i < NL; ++i) {
        const float* cwi  = conv_w + (size_t)i * DI * DC;
        const float* cbi  = conv_b + (size_t)i * DI;
        const float* Wdti = W_dt  + (size_t)i * DI * DTR;
        const float* bdti = b_dt  + (size_t)i * DI;
        const float* Ali  = A_log + (size_t)i * DI * DS;
        const float* Dski = D_skip + (size_t)i * DI;

        if (!all) {
            cvt_bf16_kernel<<<(int)(WIN_L/4/256), 256, 0, stream>>>(
                W_in + (size_t)i*WIN_L, Win_b, (int)WIN_L);
            cvt_bf16_kernel<<<(int)(WOUT_L/4/256), 256, 0, stream>>>(
                W_out + (size_t)i*WOUT_L, Wout_b, (int)WOUT_L);
            cvt_padrow_kernel<<<(int)(WXP_L/4/256), 256, 0, stream>>>(
                W_x + (size_t)i*WXROWS*DI, Wxp_b, WXROWS, 128, DI, 1);
        }
        const __hip_bfloat16* Win_l  = Win_b  + (all ? (size_t)i*WIN_L  : 0);
        const __hip_bfloat16* Wout_l = Wout_b + (all ? (size_t)i*WOUT_L : 0);
        const __hip_bfloat16* Wxp_l  = Wxp_b  + (all ? (size_t)i*WXP_L  : 0);

        // 2) xz = xn @ W_in^T  (MFMA 64M-tile, bf16 out, swizzled; 768 blocks)
        gemm_mfma_kernel<<<(2*DI/128)*(NTOK/64), 256, 0, stream>>>(
            xn_bf, Win_l, xz_bf, 2*DI/128, NTOK, 2*DI, DM);
        // 3) vectorized causal conv + SiLU -> u_bf (1536 blocks)
        conv_silu_kernel<<<(NTOK*DI/8 + 255)/256, 256, 0, stream>>>(xz_bf, cwi, cbi, u_bf);
        // 4) dbl-partials = u @ W_x^T  (MFMA 64M-tile split-K; 256 blocks)
        gemm_mfma_skinny<<<dim3(SKS, NTOK/64), 256, 0, stream>>>(u_bf, Wxp_l, dblp);
        // 5) fused split-K reduce + delta (1536 blocks)
        reduce_delta_kernel<<<dim3(DI/256, NTOK/DTB), 256, 0, stream>>>(
            dblp, Wdti, bdti, dbl, delta_bf);
        // 6) chunk-parallel scan (NC=64; phaseB wave-parallel, 12288 blocks)
        scan_phaseA<<<dim3(DI/256, NC, BB), 256, 0, stream>>>(
            delta_bf, u_bf, dbl, Ali, Psum, Hsum);
        scan_phaseB<<<(BB*DI*DS*64 + 255)/256, 256, 0, stream>>>(Psum, Hsum, Hin);
        scan_phaseC<<<dim3(DI/256, NC, BB), 256, 0, stream>>>(
            delta_bf, u_bf, dbl, xz_bf, Ali, Dski, Hin, y_bf);
        // 7) h += y @ W_out^T  (64M-tile split-K=3, 576 blocks) + fused reduce/residual/norm
        gemm_mfma_splitk4<<<SK4*(NTOK/64)*(DM/128), 256, 0, stream>>>(
            y_bf, Wout_l, Cp4);
        reduce_add_norm_kernel<<<NTOK, 256, 0, stream>>>(
            Cp4, h, (i < NL-1) ? (norm_w + (size_t)(i+1)*DM) : nullptr, xn_bf);
    }

    final_kernel<<<BB, 256, 0, stream>>>(h, normf_w, lengths, out);
}

// Round 15
// 1106.975 us; speedup vs baseline: 1.2540x; 1.2540x over previous
//
#include <hip/hip_runtime.h>
#include <hip/hip_bf16.h>
#include <math.h>

// Problem dims (fixed)
#define BB 2
#define LL 1024
#define DM 768
#define NL 8
#define DS 16
#define DC 4
#define DI 1536
#define DTR 48
#define NTOK (BB*LL)          // 2048
#define WXROWS (DTR + 2*DS)   // 80
#define NC 64                 // scan chunks
#define CT (LL/NC)            // 16 timesteps per chunk
#define SKS 8                 // split-K for W_x GEMM
#define SKC (DI/SKS)          // 192 per split
#define SK4 3                 // split-K for W_out GEMM
#define SK4C (DI/SK4)         // 512 per split
#define DTB 8                 // tokens per delta-kernel block
#define RBLK 128              // r-values per phaseB block

typedef __attribute__((ext_vector_type(8))) short bf16x8;
typedef __attribute__((ext_vector_type(4))) float f32x4;

__device__ inline void gload_lds16(const void* g, void* l) {
    __builtin_amdgcn_global_load_lds(
        (const __attribute__((address_space(1))) unsigned int*)g,
        (__attribute__((address_space(3))) unsigned int*)l, 16, 0, 0);
}

// bijective XCD swizzle for nwg % 8 == 0
__device__ inline int xcd_swz(int orig, int nwg) {
    return (orig & 7) * (nwg >> 3) + (orig >> 3);
}

// ---------------- MFMA core: 64(M) x 128(N) tile, BK=32, single buffer ----------------
__device__ inline void gemm_core64(
    const __hip_bfloat16* __restrict__ gA0,
    const __hip_bfloat16* __restrict__ gW0, const __hip_bfloat16* __restrict__ gW1,
    int kbeg, int kend, int w, int wr, int wc, int fr, int khi,
    f32x4 (&acc)[2][4])
{
    __shared__ short As[2048];
    __shared__ short Ws[4096];
    short* AsW = As + w * 512;
    short* WsW = Ws + w * 512;
    for (int k0 = kbeg; k0 < kend; k0 += 32) {
        gload_lds16(gA0 + k0, AsW);
        gload_lds16(gW0 + k0, WsW);
        gload_lds16(gW1 + k0, WsW + 2048);
        asm volatile("s_waitcnt vmcnt(0)" ::: "memory");
        __syncthreads();
        bf16x8 a4[2], b4[4];
        #pragma unroll
        for (int mi = 0; mi < 2; ++mi)
            a4[mi] = *(const bf16x8*)&As[(wr*32 + mi*16 + fr)*32 + khi*8];
        #pragma unroll
        for (int ni = 0; ni < 4; ++ni)
            b4[ni] = *(const bf16x8*)&Ws[(wc*64 + ni*16 + fr)*32 + khi*8];
        #pragma unroll
        for (int mi = 0; mi < 2; ++mi)
            #pragma unroll
            for (int ni = 0; ni < 4; ++ni)
                acc[mi][ni] = __builtin_amdgcn_mfma_f32_16x16x32_bf16(
                    a4[mi], b4[ni], acc[mi][ni], 0, 0, 0);
        __syncthreads();
    }
}

// ---------------- tiled input transpose: batch[b,d,l] -> h[b,l,d] ----------------
__global__ __launch_bounds__(256) void transpose_in_kernel(
    const float* __restrict__ batch, float* __restrict__ h)
{
    __shared__ float tile[32][33];
    const int b  = blockIdx.z;
    const int l0 = blockIdx.x * 32;
    const int d0 = blockIdx.y * 32;
    const int tx = threadIdx.x & 31;
    const int ty = threadIdx.x >> 5;          // 0..7
    #pragma unroll
    for (int i = ty; i < 32; i += 8)
        tile[i][tx] = batch[((size_t)b*DM + d0 + i)*LL + l0 + tx];
    __syncthreads();
    #pragma unroll
    for (int i = ty; i < 32; i += 8)
        h[((size_t)b*LL + l0 + i)*DM + d0 + tx] = tile[tx][i];
}

// ---------------- lengths from mask (robust to bool vs int32) ----------------
__global__ void lengths_kernel(const void* __restrict__ mask, int* __restrict__ lengths)
{
    int b = threadIdx.x;
    if (b >= BB) return;
    const unsigned int* mi = (const unsigned int*)mask;
    bool packed = (mi[0] == 0x01010101u);
    int cnt = 0;
    if (packed) {
        const unsigned char* mb = (const unsigned char*)mask;
        for (int i = 0; i < LL; ++i) cnt += (mb[(size_t)b*LL + i] != 0);
    } else {
        for (int i = 0; i < LL; ++i) cnt += (mi[(size_t)b*LL + i] != 0);
    }
    lengths[b] = cnt;
}

// ---------------- f32 -> bf16 conversions ----------------
__global__ __launch_bounds__(256) void cvt_bf16_kernel(
    const float* __restrict__ in, __hip_bfloat16* __restrict__ o, int n)
{
    int i = (blockIdx.x * 256 + threadIdx.x) * 4;
    if (i >= n) return;
    float4 v = *(const float4*)(in + i);
    __hip_bfloat16 h0 = __float2bfloat16(v.x);
    __hip_bfloat16 h1 = __float2bfloat16(v.y);
    __hip_bfloat16 h2 = __float2bfloat16(v.z);
    __hip_bfloat16 h3 = __float2bfloat16(v.w);
    ushort4 r;
    r.x = *(unsigned short*)&h0; r.y = *(unsigned short*)&h1;
    r.z = *(unsigned short*)&h2; r.w = *(unsigned short*)&h3;
    *(ushort4*)(o + i) = r;
}

__global__ __launch_bounds__(256) void cvt_padrow_kernel(
    const float* __restrict__ in, __hip_bfloat16* __restrict__ o,
    int nrin, int nrout, int ncol, int nmat)
{
    int i = (blockIdx.x * 256 + threadIdx.x) * 4;
    int tot = nmat * nrout * ncol;
    if (i >= tot) return;
    int m = i / (nrout * ncol);
    int rem = i - m * (nrout * ncol);
    int r = rem / ncol;
    int c = rem - r * ncol;
    ushort4 rr = {0,0,0,0};
    if (r < nrin) {
        float4 v = *(const float4*)(in + ((size_t)m*nrin + r)*ncol + c);
        __hip_bfloat16 h0 = __float2bfloat16(v.x);
        __hip_bfloat16 h1 = __float2bfloat16(v.y);
        __hip_bfloat16 h2 = __float2bfloat16(v.z);
        __hip_bfloat16 h3 = __float2bfloat16(v.w);
        rr.x = *(unsigned short*)&h0; rr.y = *(unsigned short*)&h1;
        rr.z = *(unsigned short*)&h2; rr.w = *(unsigned short*)&h3;
    }
    *(ushort4*)(o + i) = rr;
}

// ---------------- RMSNorm (per token, D=768) -> bf16 out ----------------
__global__ __launch_bounds__(256) void rmsnorm_kernel(
    const float* __restrict__ x, const float* __restrict__ w,
    __hip_bfloat16* __restrict__ o)
{
    int tok = blockIdx.x;
    const float* xr = x + (size_t)tok * DM;
    float ss = 0.f;
    for (int j = threadIdx.x; j < DM; j += 256) { float v = xr[j]; ss += v*v; }
    #pragma unroll
    for (int off = 32; off > 0; off >>= 1) ss += __shfl_down(ss, off);
    __shared__ float red[4];
    int lane = threadIdx.x & 63, wv = threadIdx.x >> 6;
    if (lane == 0) red[wv] = ss;
    __syncthreads();
    if (threadIdx.x == 0) {
        float t = red[0] + red[1] + red[2] + red[3];
        red[0] = rsqrtf(t / (float)DM + 1e-5f);
    }
    __syncthreads();
    float r = red[0];
    for (int j = threadIdx.x; j < DM; j += 256)
        o[(size_t)tok*DM + j] = __float2bfloat16(xr[j] * w[j] * r);
}

// ---------------- MFMA bf16 GEMM (full K, 64M x 128N tiles, swizzled): C = A @ W^T ----------------
__global__ __launch_bounds__(256) void gemm_mfma_kernel(
    const __hip_bfloat16* __restrict__ A,
    const __hip_bfloat16* __restrict__ W,
    __hip_bfloat16* __restrict__ C,
    int NT, int M, int N, int K)
{
    const int swz = xcd_swz(blockIdx.x, gridDim.x);
    const int bn = (swz % NT) * 128;
    const int bm = (swz / NT) * 64;
    const int t = threadIdx.x;
    const int w = t >> 6;
    const int lane = t & 63;
    const int wr = w >> 1, wc = w & 1;
    const int fr = lane & 15;
    const int khi = lane >> 4;

    f32x4 acc[2][4];
    #pragma unroll
    for (int mi = 0; mi < 2; ++mi)
        #pragma unroll
        for (int ni = 0; ni < 4; ++ni)
            acc[mi][ni] = (f32x4){0.f, 0.f, 0.f, 0.f};

    const int rowL = t >> 2;
    const int ks = (t & 3) * 8;
    gemm_core64(A + (size_t)(bm + rowL) * K + ks,
                W + (size_t)(bn + rowL) * K + ks,
                W + (size_t)(bn + 64 + rowL) * K + ks,
                0, K, w, wr, wc, fr, khi, acc);

    #pragma unroll
    for (int mi = 0; mi < 2; ++mi) {
        #pragma unroll
        for (int ni = 0; ni < 4; ++ni) {
            int gc = bn + wc*64 + ni*16 + fr;
            #pragma unroll
            for (int r = 0; r < 4; ++r) {
                int gr = bm + wr*32 + mi*16 + khi*4 + r;
                C[(size_t)gr * N + gc] = __float2bfloat16(acc[mi][ni][r]);
            }
        }
    }
}

// ---------------- W_out GEMM split-K=3, 64M tiles, swizzled 1D grid (576 blocks) ----------------
__global__ __launch_bounds__(256) void gemm_mfma_splitk4(
    const __hip_bfloat16* __restrict__ A,
    const __hip_bfloat16* __restrict__ W,
    float* __restrict__ Cp)
{
    const int swz = xcd_swz(blockIdx.x, gridDim.x);
    const int bm = (swz / 18) * 64;
    const int r18 = swz % 18;
    const int bn = (r18 % 6) * 128;
    const int split = r18 / 6;
    const int t = threadIdx.x;
    const int w = t >> 6;
    const int lane = t & 63;
    const int wr = w >> 1, wc = w & 1;
    const int fr = lane & 15;
    const int khi = lane >> 4;

    f32x4 acc[2][4];
    #pragma unroll
    for (int mi = 0; mi < 2; ++mi)
        #pragma unroll
        for (int ni = 0; ni < 4; ++ni)
            acc[mi][ni] = (f32x4){0.f, 0.f, 0.f, 0.f};

    const int rowL = t >> 2;
    const int ks = (t & 3) * 8;
    const int kbeg = split * SK4C;
    gemm_core64(A + (size_t)(bm + rowL) * DI + ks,
                W + (size_t)(bn + rowL) * DI + ks,
                W + (size_t)(bn + 64 + rowL) * DI + ks,
                kbeg, kbeg + SK4C, w, wr, wc, fr, khi, acc);

    #pragma unroll
    for (int mi = 0; mi < 2; ++mi) {
        #pragma unroll
        for (int ni = 0; ni < 4; ++ni) {
            int gc = bn + wc*64 + ni*16 + fr;
            #pragma unroll
            for (int r = 0; r < 4; ++r) {
                int gr = bm + wr*32 + mi*16 + khi*4 + r;
                Cp[((size_t)split*NTOK + gr)*DM + gc] = acc[mi][ni][r];
            }
        }
    }
}

// reduce split-K partials + residual add + next-layer RMSNorm (fused)
__global__ __launch_bounds__(256) void reduce_add_norm_kernel(
    const float* __restrict__ Cp, float* __restrict__ h,
    const float* __restrict__ nw, __hip_bfloat16* __restrict__ xn)
{
    int tok = blockIdx.x;
    int tid = threadIdx.x;
    float v[3];
    float ss = 0.f;
    #pragma unroll
    for (int r = 0; r < 3; ++r) {
        int j = tid + r*256;
        size_t o = (size_t)tok*DM + j;
        float x = h[o] + Cp[o] + Cp[(size_t)NTOK*DM + o] + Cp[2*(size_t)NTOK*DM + o];
        h[o] = x;
        v[r] = x;
        ss += x*x;
    }
    if (!nw) return;
    #pragma unroll
    for (int off = 32; off > 0; off >>= 1) ss += __shfl_down(ss, off);
    __shared__ float red[4];
    int lane = tid & 63, wv = tid >> 6;
    if (lane == 0) red[wv] = ss;
    __syncthreads();
    if (tid == 0) {
        float t = red[0] + red[1] + red[2] + red[3];
        red[0] = rsqrtf(t / (float)DM + 1e-5f);
    }
    __syncthreads();
    float rinv = red[0];
    #pragma unroll
    for (int r = 0; r < 3; ++r) {
        int j = tid + r*256;
        xn[(size_t)tok*DM + j] = __float2bfloat16(v[r] * nw[j] * rinv);
    }
}

// ---------------- skinny MFMA split-K GEMM (64M tiles): dblp[split][m][0..79] ----------------
__global__ __launch_bounds__(256) void gemm_mfma_skinny(
    const __hip_bfloat16* __restrict__ A,
    const __hip_bfloat16* __restrict__ W,
    float* __restrict__ Cp)
{
    const int split = blockIdx.x;
    const int bm = blockIdx.y * 64;
    const int t = threadIdx.x;
    const int w = t >> 6;
    const int lane = t & 63;
    const int wr = w >> 1, wc = w & 1;
    const int fr = lane & 15;
    const int khi = lane >> 4;

    f32x4 acc[2][4];
    #pragma unroll
    for (int mi = 0; mi < 2; ++mi)
        #pragma unroll
        for (int ni = 0; ni < 4; ++ni)
            acc[mi][ni] = (f32x4){0.f, 0.f, 0.f, 0.f};

    const int rowL = t >> 2;
    const int ks = (t & 3) * 8;
    const int kbeg = split * SKC;
    gemm_core64(A + (size_t)(bm + rowL) * DI + ks,
                W + (size_t)rowL * DI + ks,
                W + (size_t)(64 + rowL) * DI + ks,
                kbeg, kbeg + SKC, w, wr, wc, fr, khi, acc);

    #pragma unroll
    for (int mi = 0; mi < 2; ++mi) {
        #pragma unroll
        for (int ni = 0; ni < 4; ++ni) {
            int gc = wc*64 + ni*16 + fr;
            if (gc >= WXROWS) continue;
            #pragma unroll
            for (int r = 0; r < 4; ++r) {
                int gr = bm + wr*32 + mi*16 + khi*4 + r;
                Cp[((size_t)split*NTOK + gr)*WXROWS + gc] = acc[mi][ni][r];
            }
        }
    }
}

// ---------------- fused split-K reduce + delta ----------------
__global__ __launch_bounds__(256) void reduce_delta_kernel(
    const float* __restrict__ Cp,
    const float* __restrict__ W_dt, const float* __restrict__ b_dt,
    float* __restrict__ dbl, __hip_bfloat16* __restrict__ delta)
{
    __shared__ float ld[DTB*DTR];
    const int tid = threadIdx.x;
    const int d = blockIdx.x * 256 + tid;
    const int t0 = blockIdx.y * DTB;
    for (int j = tid; j < DTB*DTR; j += 256) {
        int tt = j / DTR, jj = j - tt*DTR;
        float s = 0.f;
        #pragma unroll
        for (int p = 0; p < SKS; ++p)
            s += Cp[((size_t)p*NTOK + t0 + tt)*WXROWS + jj];
        ld[j] = s;
    }
    if (blockIdx.x == 0) {
        for (int j = tid; j < DTB*WXROWS; j += 256) {
            int tt = j / WXROWS, jj = j - tt*WXROWS;
            float s = 0.f;
            #pragma unroll
            for (int p = 0; p < SKS; ++p)
                s += Cp[((size_t)p*NTOK + t0 + tt)*WXROWS + jj];
            dbl[(size_t)(t0 + tt)*WXROWS + jj] = s;
        }
    }
    float wdt[DTR];
    #pragma unroll
    for (int j = 0; j < DTR; j += 4) {
        float4 v = *(const float4*)(W_dt + (size_t)d*DTR + j);
        wdt[j] = v.x; wdt[j+1] = v.y; wdt[j+2] = v.z; wdt[j+3] = v.w;
    }
    const float bdt = b_dt[d];
    __syncthreads();
    #pragma unroll
    for (int tt = 0; tt < DTB; ++tt) {
        float dt = bdt;
        #pragma unroll
        for (int j = 0; j < DTR; ++j) dt = fmaf(ld[tt*DTR + j], wdt[j], dt);
        dt = (dt > 20.f) ? dt : log1pf(__expf(dt));
        delta[(size_t)(t0 + tt)*DI + d] = __float2bfloat16(dt);
    }
}

// ---------------- vectorized causal depthwise conv4 + bias + SiLU (8 ch/thread) ----------------
__global__ __launch_bounds__(256) void conv_silu_kernel(
    const __hip_bfloat16* __restrict__ xz, const float* __restrict__ cw,
    const float* __restrict__ cb, __hip_bfloat16* __restrict__ u)
{
    int idx = blockIdx.x * 256 + threadIdx.x;      // NTOK*DI/8 threads
    if (idx >= NTOK*DI/8) return;
    const int dg  = idx % (DI/8);
    const int row = idx / (DI/8);                   // b*LL + l
    const int l   = row % LL;
    const int d0  = dg * 8;

    float acc[8];
    {
        float4 c0 = *(const float4*)(cb + d0);
        float4 c1 = *(const float4*)(cb + d0 + 4);
        acc[0]=c0.x; acc[1]=c0.y; acc[2]=c0.z; acc[3]=c0.w;
        acc[4]=c1.x; acc[5]=c1.y; acc[6]=c1.z; acc[7]=c1.w;
    }
    float4 cwj[8];
    #pragma unroll
    for (int j = 0; j < 8; ++j)
        cwj[j] = *(const float4*)(cw + (size_t)(d0 + j)*4);

    #pragma unroll
    for (int k = 0; k < 4; ++k) {
        int ls = l - 3 + k;
        if (ls < 0) continue;
        bf16x8 v = *(const bf16x8*)(xz + (size_t)(row - 3 + k)*(2*DI) + d0);
        const __hip_bfloat16* vp = (const __hip_bfloat16*)&v;
        #pragma unroll
        for (int j = 0; j < 8; ++j) {
            float xv = __bfloat162float(vp[j]);
            float wv = (k == 0) ? cwj[j].x : (k == 1) ? cwj[j].y : (k == 2) ? cwj[j].z : cwj[j].w;
            acc[j] = fmaf(xv, wv, acc[j]);
        }
    }
    bf16x8 r;
    __hip_bfloat16* rp = (__hip_bfloat16*)&r;
    #pragma unroll
    for (int j = 0; j < 8; ++j) {
        float s = acc[j] / (1.f + __expf(-acc[j]));
        rp[j] = __float2bfloat16(s);
    }
    *(bf16x8*)(u + (size_t)row*DI + d0) = r;
}

// ================= chunk-parallel selective scan (delta precomputed bf16, NC=64) =================
__global__ __launch_bounds__(256) void scan_phaseA(
    const __hip_bfloat16* __restrict__ delta, const __hip_bfloat16* __restrict__ u,
    const float* __restrict__ dbl, const float* __restrict__ A_log,
    float* __restrict__ Psum, float* __restrict__ Hsum)
{
    const int d = blockIdx.x * 256 + threadIdx.x;
    const int c = blockIdx.y;
    const int b = blockIdx.z;
    float A[DS], P[DS], hl[DS];
    #pragma unroll
    for (int s = 0; s < DS; ++s) {
        A[s] = -expf(A_log[(size_t)d*DS + s]);
        P[s] = 1.f; hl[s] = 0.f;
    }
    const int t0 = c * CT;
    for (int t = t0; t < t0 + CT; ++t) {
        const size_t row = (size_t)b*LL + t;
        const float* bc = dbl + row*WXROWS + DTR;
        float dt = __bfloat162float(delta[row*DI + d]);
        float du = dt * __bfloat162float(u[row*DI + d]);
        #pragma unroll
        for (int s = 0; s < DS; ++s) {
            float a = __expf(dt * A[s]);
            P[s] *= a;
            hl[s] = fmaf(a, hl[s], du * bc[s]);
        }
    }
    const size_t off = (((size_t)b*NC + c)*DI + d)*DS;
    #pragma unroll
    for (int s = 0; s < DS; ++s) { Psum[off+s] = P[s]; Hsum[off+s] = hl[s]; }
}

// LDS-staged phaseB: one block per (b, 128 consecutive r). Coalesced global loads,
// serial 64-chunk recurrence runs in LDS (threads 0..127), coalesced Hin stores.
__global__ __launch_bounds__(256) void scan_phaseB(
    const float* __restrict__ Psum, const float* __restrict__ Hsum,
    float* __restrict__ Hin)
{
    __shared__ float pA[NC][RBLK];
    __shared__ float hA[NC][RBLK];
    const int tid = threadIdx.x;
    const int blk = blockIdx.x;                 // 0 .. BB*DI*DS/RBLK - 1
    const int b = blk / (DI*DS/RBLK);
    const int r0 = (blk % (DI*DS/RBLK)) * RBLK;
    // coalesced stage: for each chunk c, 128 consecutive floats
    for (int j = tid; j < NC*RBLK; j += 256) {
        int c = j >> 7, rr = j & (RBLK-1);
        size_t off = ((size_t)(b*NC + c))*DI*DS + r0 + rr;
        pA[c][rr] = Psum[off];
        hA[c][rr] = Hsum[off];
    }
    __syncthreads();
    if (tid < RBLK) {
        float hc = 0.f;
        for (int c = 0; c < NC; ++c) {
            size_t off = ((size_t)(b*NC + c))*DI*DS + r0 + tid;
            Hin[off] = hc;
            hc = fmaf(pA[c][tid], hc, hA[c][tid]);
        }
    }
}

__global__ __launch_bounds__(256) void scan_phaseC(
    const __hip_bfloat16* __restrict__ delta, const __hip_bfloat16* __restrict__ u,
    const float* __restrict__ dbl, const __hip_bfloat16* __restrict__ xz,
    const float* __restrict__ A_log, const float* __restrict__ Dsk,
    const float* __restrict__ Hin, __hip_bfloat16* __restrict__ yfull)
{
    const int d = blockIdx.x * 256 + threadIdx.x;
    const int c = blockIdx.y;
    const int b = blockIdx.z;
    float A[DS], h[DS];
    const size_t hoff = (((size_t)b*NC + c)*DI + d)*DS;
    #pragma unroll
    for (int s = 0; s < DS; ++s) {
        A[s] = -expf(A_log[(size_t)d*DS + s]);
        h[s] = Hin[hoff + s];
    }
    const float dsk = Dsk[d];
    const int t0 = c * CT;
    for (int t = t0; t < t0 + CT; ++t) {
        const size_t row = (size_t)b*LL + t;
        const float* bc = dbl + row*WXROWS + DTR;
        float dt = __bfloat162float(delta[row*DI + d]);
        float ut = __bfloat162float(u[row*DI + d]);
        float du = dt * ut;
        float y = 0.f;
        #pragma unroll
        for (int s = 0; s < DS; ++s) {
            float a = __expf(dt * A[s]);
            h[s] = fmaf(a, h[s], du * bc[s]);
            y = fmaf(h[s], bc[DS+s], y);
        }
        float zt = __bfloat162float(xz[row*(2*DI) + DI + d]);
        float sz = zt / (1.f + __expf(-zt));
        yfull[row*DI + d] = __float2bfloat16((y + ut * dsk) * sz);
    }
}

// ---------------- final rmsnorm + gather last valid token ----------------
__global__ __launch_bounds__(256) void final_kernel(
    const float* __restrict__ h, const float* __restrict__ w,
    const int* __restrict__ lengths, float* __restrict__ out)
{
    int b = blockIdx.x;
    int idx = lengths[b] - 1;
    const float* xr = h + ((size_t)b*LL + idx)*DM;
    float ss = 0.f;
    for (int j = threadIdx.x; j < DM; j += 256) { float v = xr[j]; ss += v*v; }
    #pragma unroll
    for (int off = 32; off > 0; off >>= 1) ss += __shfl_down(ss, off);
    __shared__ float red[4];
    int lane = threadIdx.x & 63, wv = threadIdx.x >> 6;
    if (lane == 0) red[wv] = ss;
    __syncthreads();
    if (threadIdx.x == 0) {
        float t = red[0] + red[1] + red[2] + red[3];
        red[0] = rsqrtf(t / (float)DM + 1e-5f);
    }
    __syncthreads();
    float r = red[0];
    for (int j = threadIdx.x; j < DM; j += 256)
        out[(size_t)b*DM + j] = xr[j] * w[j] * r;
}

extern "C" void kernel_launch(void* const* d_in, const int* in_sizes, int n_in,
                              void* d_out, int out_size, void* d_ws, size_t ws_size,
                              hipStream_t stream)
{
    const float* batch   = (const float*)d_in[0];
    const void*  mask    = d_in[1];
    const float* norm_w  = (const float*)d_in[2];
    const float* W_in    = (const float*)d_in[3];
    const float* conv_w  = (const float*)d_in[4];
    const float* conv_b  = (const float*)d_in[5];
    const float* W_x     = (const float*)d_in[6];
    const float* W_dt    = (const float*)d_in[7];
    const float* b_dt    = (const float*)d_in[8];
    const float* A_log   = (const float*)d_in[9];
    const float* D_skip  = (const float*)d_in[10];
    const float* W_out   = (const float*)d_in[11];
    const float* normf_w = (const float*)d_in[12];
    float* out = (float*)d_out;

    // ---------------- workspace layout ----------------
    float* ws   = (float*)d_ws;
    float* h    = ws;                            // NTOK*DM f32
    float* dbl  = h   + (size_t)NTOK*DM;         // NTOK*80 f32
    float* scr  = dbl + (size_t)NTOK*WXROWS;     // 3*SEG f32 (aliased scratch)
    const size_t SEG = (size_t)BB*NC*DI*DS;      // 3,145,728 (NC=64)
    float* dblp = scr;                           // [SKS][NTOK][80]
    float* Psum = scr;
    float* Hsum = scr + SEG;
    float* Hin  = scr + 2*SEG;
    float* Cp4  = scr;                           // [SK4][NTOK][DM]
    __hip_bfloat16* xz_bf    = (__hip_bfloat16*)(scr + 3*SEG);
    __hip_bfloat16* xn_bf    = xz_bf + (size_t)NTOK*2*DI;
    __hip_bfloat16* u_bf     = xn_bf + (size_t)NTOK*DM;
    __hip_bfloat16* delta_bf = u_bf  + (size_t)NTOK*DI;
    __hip_bfloat16* y_bf     = delta_bf + (size_t)NTOK*DI;
    __hip_bfloat16* wbase    = y_bf + (size_t)NTOK*DI;

    const size_t WIN_L  = (size_t)2*DI*DM;
    const size_t WOUT_L = (size_t)DM*DI;
    const size_t WXP_L  = (size_t)128*DI;
    const size_t WSUM   = WIN_L + WOUT_L + WXP_L;

    size_t need_all = (size_t)((char*)(wbase + (size_t)NL*WSUM) - (char*)d_ws) + 256;
    const bool all = ws_size >= need_all;
    const int nlw = all ? NL : 1;

    __hip_bfloat16* Win_b  = wbase;
    __hip_bfloat16* Wout_b = Win_b  + (size_t)nlw*WIN_L;
    __hip_bfloat16* Wxp_b  = Wout_b + (size_t)nlw*WOUT_L;
    int* lengths = (int*)(Wxp_b + (size_t)nlw*WXP_L);

    transpose_in_kernel<<<dim3(LL/32, DM/32, BB), 256, 0, stream>>>(batch, h);
    lengths_kernel<<<1, 64, 0, stream>>>(mask, lengths);

    if (all) {
        cvt_bf16_kernel<<<(int)(NL*WIN_L/4/256), 256, 0, stream>>>(W_in, Win_b, (int)(NL*WIN_L));
        cvt_bf16_kernel<<<(int)(NL*WOUT_L/4/256), 256, 0, stream>>>(W_out, Wout_b, (int)(NL*WOUT_L));
        cvt_padrow_kernel<<<(int)(NL*WXP_L/4/256), 256, 0, stream>>>(
            W_x, Wxp_b, WXROWS, 128, DI, NL);
    }

    // layer-0 pre-norm
    rmsnorm_kernel<<<NTOK, 256, 0, stream>>>(h, norm_w, xn_bf);

    for (int i = 0; i < NL; ++i) {
        const float* cwi  = conv_w + (size_t)i * DI * DC;
        const float* cbi  = conv_b + (size_t)i * DI;
        const float* Wdti = W_dt  + (size_t)i * DI * DTR;
        const float* bdti = b_dt  + (size_t)i * DI;
        const float* Ali  = A_log + (size_t)i * DI * DS;
        const float* Dski = D_skip + (size_t)i * DI;

        if (!all) {
            cvt_bf16_kernel<<<(int)(WIN_L/4/256), 256, 0, stream>>>(
                W_in + (size_t)i*WIN_L, Win_b, (int)WIN_L);
            cvt_bf16_kernel<<<(int)(WOUT_L/4/256), 256, 0, stream>>>(
                W_out + (size_t)i*WOUT_L, Wout_b, (int)WOUT_L);
            cvt_padrow_kernel<<<(int)(WXP_L/4/256), 256, 0, stream>>>(
                W_x + (size_t)i*WXROWS*DI, Wxp_b, WXROWS, 128, DI, 1);
        }
        const __hip_bfloat16* Win_l  = Win_b  + (all ? (size_t)i*WIN_L  : 0);
        const __hip_bfloat16* Wout_l = Wout_b + (all ? (size_t)i*WOUT_L : 0);
        const __hip_bfloat16* Wxp_l  = Wxp_b  + (all ? (size_t)i*WXP_L  : 0);

        // 2) xz = xn @ W_in^T  (MFMA 64M-tile, bf16 out, swizzled; 768 blocks)
        gemm_mfma_kernel<<<(2*DI/128)*(NTOK/64), 256, 0, stream>>>(
            xn_bf, Win_l, xz_bf, 2*DI/128, NTOK, 2*DI, DM);
        // 3) vectorized causal conv + SiLU -> u_bf (1536 blocks)
        conv_silu_kernel<<<(NTOK*DI/8 + 255)/256, 256, 0, stream>>>(xz_bf, cwi, cbi, u_bf);
        // 4) dbl-partials = u @ W_x^T  (MFMA 64M-tile split-K; 256 blocks)
        gemm_mfma_skinny<<<dim3(SKS, NTOK/64), 256, 0, stream>>>(u_bf, Wxp_l, dblp);
        // 5) fused split-K reduce + delta (1536 blocks)
        reduce_delta_kernel<<<dim3(DI/256, NTOK/DTB), 256, 0, stream>>>(
            dblp, Wdti, bdti, dbl, delta_bf);
        // 6) chunk-parallel scan (NC=64; phaseB LDS-staged, 384 blocks)
        scan_phaseA<<<dim3(DI/256, NC, BB), 256, 0, stream>>>(
            delta_bf, u_bf, dbl, Ali, Psum, Hsum);
        scan_phaseB<<<BB*DI*DS/RBLK, 256, 0, stream>>>(Psum, Hsum, Hin);
        scan_phaseC<<<dim3(DI/256, NC, BB), 256, 0, stream>>>(
            delta_bf, u_bf, dbl, xz_bf, Ali, Dski, Hin, y_bf);
        // 7) h += y @ W_out^T  (64M-tile split-K=3, 576 blocks) + fused reduce/residual/norm
        gemm_mfma_splitk4<<<SK4*(NTOK/64)*(DM/128), 256, 0, stream>>>(
            y_bf, Wout_l, Cp4);
        reduce_add_norm_kernel<<<NTOK, 256, 0, stream>>>(
            Cp4, h, (i < NL-1) ? (norm_w + (size_t)(i+1)*DM) : nullptr, xn_bf);
    }

    final_kernel<<<BB, 256, 0, stream>>>(h, normf_w, lengths, out);
}

// Round 16
// 1064.467 us; speedup vs baseline: 1.3041x; 1.0399x over previous
//
#include <hip/hip_runtime.h>
#include <hip/hip_bf16.h>
#include <math.h>

// Problem dims (fixed)
#define BB 2
#define LL 1024
#define DM 768
#define NL 8
#define DS 16
#define DC 4
#define DI 1536
#define DTR 48
#define NTOK (BB*LL)          // 2048
#define WXROWS (DTR + 2*DS)   // 80
#define NC 64                 // scan chunks
#define CT (LL/NC)            // 16 timesteps per chunk
#define SKS 8                 // split-K for W_x GEMM
#define SKC (DI/SKS)          // 192 per split
#define SK4 3                 // split-K for W_out GEMM
#define SK4C (DI/SK4)         // 512 per split
#define DTB 8                 // tokens per delta-kernel block
#define RBLK 128              // r-values per phaseB block

typedef __attribute__((ext_vector_type(8))) short bf16x8;
typedef __attribute__((ext_vector_type(4))) float f32x4;

__device__ inline void gload_lds16(const void* g, void* l) {
    __builtin_amdgcn_global_load_lds(
        (const __attribute__((address_space(1))) unsigned int*)g,
        (__attribute__((address_space(3))) unsigned int*)l, 16, 0, 0);
}

// bijective XCD swizzle for nwg % 8 == 0
__device__ inline int xcd_swz(int orig, int nwg) {
    return (orig & 7) * (nwg >> 3) + (orig >> 3);
}

// ---------------- MFMA core: 64(M) x 128(N) tile, BK=32, single buffer ----------------
__device__ inline void gemm_core64(
    const __hip_bfloat16* __restrict__ gA0,
    const __hip_bfloat16* __restrict__ gW0, const __hip_bfloat16* __restrict__ gW1,
    int kbeg, int kend, int w, int wr, int wc, int fr, int khi,
    f32x4 (&acc)[2][4])
{
    __shared__ short As[2048];
    __shared__ short Ws[4096];
    short* AsW = As + w * 512;
    short* WsW = Ws + w * 512;
    for (int k0 = kbeg; k0 < kend; k0 += 32) {
        gload_lds16(gA0 + k0, AsW);
        gload_lds16(gW0 + k0, WsW);
        gload_lds16(gW1 + k0, WsW + 2048);
        asm volatile("s_waitcnt vmcnt(0)" ::: "memory");
        __syncthreads();
        bf16x8 a4[2], b4[4];
        #pragma unroll
        for (int mi = 0; mi < 2; ++mi)
            a4[mi] = *(const bf16x8*)&As[(wr*32 + mi*16 + fr)*32 + khi*8];
        #pragma unroll
        for (int ni = 0; ni < 4; ++ni)
            b4[ni] = *(const bf16x8*)&Ws[(wc*64 + ni*16 + fr)*32 + khi*8];
        #pragma unroll
        for (int mi = 0; mi < 2; ++mi)
            #pragma unroll
            for (int ni = 0; ni < 4; ++ni)
                acc[mi][ni] = __builtin_amdgcn_mfma_f32_16x16x32_bf16(
                    a4[mi], b4[ni], acc[mi][ni], 0, 0, 0);
        __syncthreads();
    }
}

// ---------------- tiled input transpose: batch[b,d,l] -> h[b,l,d] ----------------
__global__ __launch_bounds__(256) void transpose_in_kernel(
    const float* __restrict__ batch, float* __restrict__ h)
{
    __shared__ float tile[32][33];
    const int b  = blockIdx.z;
    const int l0 = blockIdx.x * 32;
    const int d0 = blockIdx.y * 32;
    const int tx = threadIdx.x & 31;
    const int ty = threadIdx.x >> 5;          // 0..7
    #pragma unroll
    for (int i = ty; i < 32; i += 8)
        tile[i][tx] = batch[((size_t)b*DM + d0 + i)*LL + l0 + tx];
    __syncthreads();
    #pragma unroll
    for (int i = ty; i < 32; i += 8)
        h[((size_t)b*LL + l0 + i)*DM + d0 + tx] = tile[tx][i];
}

// ---------------- lengths from mask (robust to bool vs int32) ----------------
__global__ void lengths_kernel(const void* __restrict__ mask, int* __restrict__ lengths)
{
    int b = threadIdx.x;
    if (b >= BB) return;
    const unsigned int* mi = (const unsigned int*)mask;
    bool packed = (mi[0] == 0x01010101u);
    int cnt = 0;
    if (packed) {
        const unsigned char* mb = (const unsigned char*)mask;
        for (int i = 0; i < LL; ++i) cnt += (mb[(size_t)b*LL + i] != 0);
    } else {
        for (int i = 0; i < LL; ++i) cnt += (mi[(size_t)b*LL + i] != 0);
    }
    lengths[b] = cnt;
}

// ---------------- f32 -> bf16 conversions ----------------
__global__ __launch_bounds__(256) void cvt_bf16_kernel(
    const float* __restrict__ in, __hip_bfloat16* __restrict__ o, int n)
{
    int i = (blockIdx.x * 256 + threadIdx.x) * 4;
    if (i >= n) return;
    float4 v = *(const float4*)(in + i);
    __hip_bfloat16 h0 = __float2bfloat16(v.x);
    __hip_bfloat16 h1 = __float2bfloat16(v.y);
    __hip_bfloat16 h2 = __float2bfloat16(v.z);
    __hip_bfloat16 h3 = __float2bfloat16(v.w);
    ushort4 r;
    r.x = *(unsigned short*)&h0; r.y = *(unsigned short*)&h1;
    r.z = *(unsigned short*)&h2; r.w = *(unsigned short*)&h3;
    *(ushort4*)(o + i) = r;
}

__global__ __launch_bounds__(256) void cvt_padrow_kernel(
    const float* __restrict__ in, __hip_bfloat16* __restrict__ o,
    int nrin, int nrout, int ncol, int nmat)
{
    int i = (blockIdx.x * 256 + threadIdx.x) * 4;
    int tot = nmat * nrout * ncol;
    if (i >= tot) return;
    int m = i / (nrout * ncol);
    int rem = i - m * (nrout * ncol);
    int r = rem / ncol;
    int c = rem - r * ncol;
    ushort4 rr = {0,0,0,0};
    if (r < nrin) {
        float4 v = *(const float4*)(in + ((size_t)m*nrin + r)*ncol + c);
        __hip_bfloat16 h0 = __float2bfloat16(v.x);
        __hip_bfloat16 h1 = __float2bfloat16(v.y);
        __hip_bfloat16 h2 = __float2bfloat16(v.z);
        __hip_bfloat16 h3 = __float2bfloat16(v.w);
        rr.x = *(unsigned short*)&h0; rr.y = *(unsigned short*)&h1;
        rr.z = *(unsigned short*)&h2; rr.w = *(unsigned short*)&h3;
    }
    *(ushort4*)(o + i) = rr;
}

// ---------------- RMSNorm (per token, D=768) -> bf16 out ----------------
__global__ __launch_bounds__(256) void rmsnorm_kernel(
    const float* __restrict__ x, const float* __restrict__ w,
    __hip_bfloat16* __restrict__ o)
{
    int tok = blockIdx.x;
    const float* xr = x + (size_t)tok * DM;
    float ss = 0.f;
    for (int j = threadIdx.x; j < DM; j += 256) { float v = xr[j]; ss += v*v; }
    #pragma unroll
    for (int off = 32; off > 0; off >>= 1) ss += __shfl_down(ss, off);
    __shared__ float red[4];
    int lane = threadIdx.x & 63, wv = threadIdx.x >> 6;
    if (lane == 0) red[wv] = ss;
    __syncthreads();
    if (threadIdx.x == 0) {
        float t = red[0] + red[1] + red[2] + red[3];
        red[0] = rsqrtf(t / (float)DM + 1e-5f);
    }
    __syncthreads();
    float r = red[0];
    for (int j = threadIdx.x; j < DM; j += 256)
        o[(size_t)tok*DM + j] = __float2bfloat16(xr[j] * w[j] * r);
}

// ---------------- MFMA bf16 GEMM (full K, 64M x 128N tiles, swizzled): C = A @ W^T ----------------
__global__ __launch_bounds__(256) void gemm_mfma_kernel(
    const __hip_bfloat16* __restrict__ A,
    const __hip_bfloat16* __restrict__ W,
    __hip_bfloat16* __restrict__ C,
    int NT, int M, int N, int K)
{
    const int swz = xcd_swz(blockIdx.x, gridDim.x);
    const int bn = (swz % NT) * 128;
    const int bm = (swz / NT) * 64;
    const int t = threadIdx.x;
    const int w = t >> 6;
    const int lane = t & 63;
    const int wr = w >> 1, wc = w & 1;
    const int fr = lane & 15;
    const int khi = lane >> 4;

    f32x4 acc[2][4];
    #pragma unroll
    for (int mi = 0; mi < 2; ++mi)
        #pragma unroll
        for (int ni = 0; ni < 4; ++ni)
            acc[mi][ni] = (f32x4){0.f, 0.f, 0.f, 0.f};

    const int rowL = t >> 2;
    const int ks = (t & 3) * 8;
    gemm_core64(A + (size_t)(bm + rowL) * K + ks,
                W + (size_t)(bn + rowL) * K + ks,
                W + (size_t)(bn + 64 + rowL) * K + ks,
                0, K, w, wr, wc, fr, khi, acc);

    #pragma unroll
    for (int mi = 0; mi < 2; ++mi) {
        #pragma unroll
        for (int ni = 0; ni < 4; ++ni) {
            int gc = bn + wc*64 + ni*16 + fr;
            #pragma unroll
            for (int r = 0; r < 4; ++r) {
                int gr = bm + wr*32 + mi*16 + khi*4 + r;
                C[(size_t)gr * N + gc] = __float2bfloat16(acc[mi][ni][r]);
            }
        }
    }
}

// ---------------- W_out GEMM split-K=3, 64M tiles, swizzled 1D grid (576 blocks) ----------------
__global__ __launch_bounds__(256) void gemm_mfma_splitk4(
    const __hip_bfloat16* __restrict__ A,
    const __hip_bfloat16* __restrict__ W,
    float* __restrict__ Cp)
{
    const int swz = xcd_swz(blockIdx.x, gridDim.x);
    const int bm = (swz / 18) * 64;
    const int r18 = swz % 18;
    const int bn = (r18 % 6) * 128;
    const int split = r18 / 6;
    const int t = threadIdx.x;
    const int w = t >> 6;
    const int lane = t & 63;
    const int wr = w >> 1, wc = w & 1;
    const int fr = lane & 15;
    const int khi = lane >> 4;

    f32x4 acc[2][4];
    #pragma unroll
    for (int mi = 0; mi < 2; ++mi)
        #pragma unroll
        for (int ni = 0; ni < 4; ++ni)
            acc[mi][ni] = (f32x4){0.f, 0.f, 0.f, 0.f};

    const int rowL = t >> 2;
    const int ks = (t & 3) * 8;
    const int kbeg = split * SK4C;
    gemm_core64(A + (size_t)(bm + rowL) * DI + ks,
                W + (size_t)(bn + rowL) * DI + ks,
                W + (size_t)(bn + 64 + rowL) * DI + ks,
                kbeg, kbeg + SK4C, w, wr, wc, fr, khi, acc);

    #pragma unroll
    for (int mi = 0; mi < 2; ++mi) {
        #pragma unroll
        for (int ni = 0; ni < 4; ++ni) {
            int gc = bn + wc*64 + ni*16 + fr;
            #pragma unroll
            for (int r = 0; r < 4; ++r) {
                int gr = bm + wr*32 + mi*16 + khi*4 + r;
                Cp[((size_t)split*NTOK + gr)*DM + gc] = acc[mi][ni][r];
            }
        }
    }
}

// reduce split-K partials + residual add + next-layer RMSNorm (fused)
__global__ __launch_bounds__(256) void reduce_add_norm_kernel(
    const float* __restrict__ Cp, float* __restrict__ h,
    const float* __restrict__ nw, __hip_bfloat16* __restrict__ xn)
{
    int tok = blockIdx.x;
    int tid = threadIdx.x;
    float v[3];
    float ss = 0.f;
    #pragma unroll
    for (int r = 0; r < 3; ++r) {
        int j = tid + r*256;
        size_t o = (size_t)tok*DM + j;
        float x = h[o] + Cp[o] + Cp[(size_t)NTOK*DM + o] + Cp[2*(size_t)NTOK*DM + o];
        h[o] = x;
        v[r] = x;
        ss += x*x;
    }
    if (!nw) return;
    #pragma unroll
    for (int off = 32; off > 0; off >>= 1) ss += __shfl_down(ss, off);
    __shared__ float red[4];
    int lane = tid & 63, wv = tid >> 6;
    if (lane == 0) red[wv] = ss;
    __syncthreads();
    if (tid == 0) {
        float t = red[0] + red[1] + red[2] + red[3];
        red[0] = rsqrtf(t / (float)DM + 1e-5f);
    }
    __syncthreads();
    float rinv = red[0];
    #pragma unroll
    for (int r = 0; r < 3; ++r) {
        int j = tid + r*256;
        xn[(size_t)tok*DM + j] = __float2bfloat16(v[r] * nw[j] * rinv);
    }
}

// ---------------- skinny MFMA split-K GEMM (64M tiles): dblp[split][m][0..79] ----------------
__global__ __launch_bounds__(256) void gemm_mfma_skinny(
    const __hip_bfloat16* __restrict__ A,
    const __hip_bfloat16* __restrict__ W,
    float* __restrict__ Cp)
{
    const int split = blockIdx.x;
    const int bm = blockIdx.y * 64;
    const int t = threadIdx.x;
    const int w = t >> 6;
    const int lane = t & 63;
    const int wr = w >> 1, wc = w & 1;
    const int fr = lane & 15;
    const int khi = lane >> 4;

    f32x4 acc[2][4];
    #pragma unroll
    for (int mi = 0; mi < 2; ++mi)
        #pragma unroll
        for (int ni = 0; ni < 4; ++ni)
            acc[mi][ni] = (f32x4){0.f, 0.f, 0.f, 0.f};

    const int rowL = t >> 2;
    const int ks = (t & 3) * 8;
    const int kbeg = split * SKC;
    gemm_core64(A + (size_t)(bm + rowL) * DI + ks,
                W + (size_t)rowL * DI + ks,
                W + (size_t)(64 + rowL) * DI + ks,
                kbeg, kbeg + SKC, w, wr, wc, fr, khi, acc);

    #pragma unroll
    for (int mi = 0; mi < 2; ++mi) {
        #pragma unroll
        for (int ni = 0; ni < 4; ++ni) {
            int gc = wc*64 + ni*16 + fr;
            if (gc >= WXROWS) continue;
            #pragma unroll
            for (int r = 0; r < 4; ++r) {
                int gr = bm + wr*32 + mi*16 + khi*4 + r;
                Cp[((size_t)split*NTOK + gr)*WXROWS + gc] = acc[mi][ni][r];
            }
        }
    }
}

// ---------------- fused split-K reduce + delta ----------------
__global__ __launch_bounds__(256) void reduce_delta_kernel(
    const float* __restrict__ Cp,
    const float* __restrict__ W_dt, const float* __restrict__ b_dt,
    float* __restrict__ dbl, __hip_bfloat16* __restrict__ delta)
{
    __shared__ float ld[DTB*DTR];
    const int tid = threadIdx.x;
    const int d = blockIdx.x * 256 + tid;
    const int t0 = blockIdx.y * DTB;
    for (int j = tid; j < DTB*DTR; j += 256) {
        int tt = j / DTR, jj = j - tt*DTR;
        float s = 0.f;
        #pragma unroll
        for (int p = 0; p < SKS; ++p)
            s += Cp[((size_t)p*NTOK + t0 + tt)*WXROWS + jj];
        ld[j] = s;
    }
    if (blockIdx.x == 0) {
        for (int j = tid; j < DTB*WXROWS; j += 256) {
            int tt = j / WXROWS, jj = j - tt*WXROWS;
            float s = 0.f;
            #pragma unroll
            for (int p = 0; p < SKS; ++p)
                s += Cp[((size_t)p*NTOK + t0 + tt)*WXROWS + jj];
            dbl[(size_t)(t0 + tt)*WXROWS + jj] = s;
        }
    }
    float wdt[DTR];
    #pragma unroll
    for (int j = 0; j < DTR; j += 4) {
        float4 v = *(const float4*)(W_dt + (size_t)d*DTR + j);
        wdt[j] = v.x; wdt[j+1] = v.y; wdt[j+2] = v.z; wdt[j+3] = v.w;
    }
    const float bdt = b_dt[d];
    __syncthreads();
    #pragma unroll
    for (int tt = 0; tt < DTB; ++tt) {
        float dt = bdt;
        #pragma unroll
        for (int j = 0; j < DTR; ++j) dt = fmaf(ld[tt*DTR + j], wdt[j], dt);
        dt = (dt > 20.f) ? dt : log1pf(__expf(dt));
        delta[(size_t)(t0 + tt)*DI + d] = __float2bfloat16(dt);
    }
}

// ---------------- vectorized causal depthwise conv4 + bias + SiLU (8 ch/thread) ----------------
__global__ __launch_bounds__(256) void conv_silu_kernel(
    const __hip_bfloat16* __restrict__ xz, const float* __restrict__ cw,
    const float* __restrict__ cb, __hip_bfloat16* __restrict__ u)
{
    int idx = blockIdx.x * 256 + threadIdx.x;      // NTOK*DI/8 threads
    if (idx >= NTOK*DI/8) return;
    const int dg  = idx % (DI/8);
    const int row = idx / (DI/8);                   // b*LL + l
    const int l   = row % LL;
    const int d0  = dg * 8;

    float acc[8];
    {
        float4 c0 = *(const float4*)(cb + d0);
        float4 c1 = *(const float4*)(cb + d0 + 4);
        acc[0]=c0.x; acc[1]=c0.y; acc[2]=c0.z; acc[3]=c0.w;
        acc[4]=c1.x; acc[5]=c1.y; acc[6]=c1.z; acc[7]=c1.w;
    }
    float4 cwj[8];
    #pragma unroll
    for (int j = 0; j < 8; ++j)
        cwj[j] = *(const float4*)(cw + (size_t)(d0 + j)*4);

    #pragma unroll
    for (int k = 0; k < 4; ++k) {
        int ls = l - 3 + k;
        if (ls < 0) continue;
        bf16x8 v = *(const bf16x8*)(xz + (size_t)(row - 3 + k)*(2*DI) + d0);
        const __hip_bfloat16* vp = (const __hip_bfloat16*)&v;
        #pragma unroll
        for (int j = 0; j < 8; ++j) {
            float xv = __bfloat162float(vp[j]);
            float wv = (k == 0) ? cwj[j].x : (k == 1) ? cwj[j].y : (k == 2) ? cwj[j].z : cwj[j].w;
            acc[j] = fmaf(xv, wv, acc[j]);
        }
    }
    bf16x8 r;
    __hip_bfloat16* rp = (__hip_bfloat16*)&r;
    #pragma unroll
    for (int j = 0; j < 8; ++j) {
        float s = acc[j] / (1.f + __expf(-acc[j]));
        rp[j] = __float2bfloat16(s);
    }
    *(bf16x8*)(u + (size_t)row*DI + d0) = r;
}

// ================= chunk-parallel selective scan (bf16 summaries, NC=64) =================
__global__ __launch_bounds__(256) void scan_phaseA(
    const __hip_bfloat16* __restrict__ delta, const __hip_bfloat16* __restrict__ u,
    const float* __restrict__ dbl, const float* __restrict__ A_log,
    __hip_bfloat16* __restrict__ Psum, __hip_bfloat16* __restrict__ Hsum)
{
    const int d = blockIdx.x * 256 + threadIdx.x;
    const int c = blockIdx.y;
    const int b = blockIdx.z;
    float A[DS], P[DS], hl[DS];
    #pragma unroll
    for (int s = 0; s < DS; ++s) {
        A[s] = -expf(A_log[(size_t)d*DS + s]);
        P[s] = 1.f; hl[s] = 0.f;
    }
    const int t0 = c * CT;
    for (int t = t0; t < t0 + CT; ++t) {
        const size_t row = (size_t)b*LL + t;
        const float* bc = dbl + row*WXROWS + DTR;
        float dt = __bfloat162float(delta[row*DI + d]);
        float du = dt * __bfloat162float(u[row*DI + d]);
        #pragma unroll
        for (int s = 0; s < DS; ++s) {
            float a = __expf(dt * A[s]);
            P[s] *= a;
            hl[s] = fmaf(a, hl[s], du * bc[s]);
        }
    }
    const size_t off = (((size_t)b*NC + c)*DI + d)*DS;
    #pragma unroll
    for (int s = 0; s < DS; ++s) {
        Psum[off+s] = __float2bfloat16(P[s]);
        Hsum[off+s] = __float2bfloat16(hl[s]);
    }
}

// LDS-staged phaseB (bf16 in/out): one block per (b, 128 consecutive r).
__global__ __launch_bounds__(256) void scan_phaseB(
    const __hip_bfloat16* __restrict__ Psum, const __hip_bfloat16* __restrict__ Hsum,
    __hip_bfloat16* __restrict__ Hin)
{
    __shared__ float pA[NC][RBLK];
    __shared__ float hA[NC][RBLK];
    const int tid = threadIdx.x;
    const int blk = blockIdx.x;
    const int b = blk / (DI*DS/RBLK);
    const int r0 = (blk % (DI*DS/RBLK)) * RBLK;
    for (int j = tid; j < NC*RBLK; j += 256) {
        int c = j >> 7, rr = j & (RBLK-1);
        size_t off = ((size_t)(b*NC + c))*DI*DS + r0 + rr;
        pA[c][rr] = __bfloat162float(Psum[off]);
        hA[c][rr] = __bfloat162float(Hsum[off]);
    }
    __syncthreads();
    if (tid < RBLK) {
        float hc = 0.f;
        for (int c = 0; c < NC; ++c) {
            size_t off = ((size_t)(b*NC + c))*DI*DS + r0 + tid;
            Hin[off] = __float2bfloat16(hc);
            hc = fmaf(pA[c][tid], hc, hA[c][tid]);
        }
    }
}

__global__ __launch_bounds__(256) void scan_phaseC(
    const __hip_bfloat16* __restrict__ delta, const __hip_bfloat16* __restrict__ u,
    const float* __restrict__ dbl, const __hip_bfloat16* __restrict__ xz,
    const float* __restrict__ A_log, const float* __restrict__ Dsk,
    const __hip_bfloat16* __restrict__ Hin, __hip_bfloat16* __restrict__ yfull)
{
    const int d = blockIdx.x * 256 + threadIdx.x;
    const int c = blockIdx.y;
    const int b = blockIdx.z;
    float A[DS], h[DS];
    const size_t hoff = (((size_t)b*NC + c)*DI + d)*DS;
    #pragma unroll
    for (int s = 0; s < DS; ++s) {
        A[s] = -expf(A_log[(size_t)d*DS + s]);
        h[s] = __bfloat162float(Hin[hoff + s]);
    }
    const float dsk = Dsk[d];
    const int t0 = c * CT;
    for (int t = t0; t < t0 + CT; ++t) {
        const size_t row = (size_t)b*LL + t;
        const float* bc = dbl + row*WXROWS + DTR;
        float dt = __bfloat162float(delta[row*DI + d]);
        float ut = __bfloat162float(u[row*DI + d]);
        float du = dt * ut;
        float y = 0.f;
        #pragma unroll
        for (int s = 0; s < DS; ++s) {
            float a = __expf(dt * A[s]);
            h[s] = fmaf(a, h[s], du * bc[s]);
            y = fmaf(h[s], bc[DS+s], y);
        }
        float zt = __bfloat162float(xz[row*(2*DI) + DI + d]);
        float sz = zt / (1.f + __expf(-zt));
        yfull[row*DI + d] = __float2bfloat16((y + ut * dsk) * sz);
    }
}

// ---------------- final rmsnorm + gather last valid token ----------------
__global__ __launch_bounds__(256) void final_kernel(
    const float* __restrict__ h, const float* __restrict__ w,
    const int* __restrict__ lengths, float* __restrict__ out)
{
    int b = blockIdx.x;
    int idx = lengths[b] - 1;
    const float* xr = h + ((size_t)b*LL + idx)*DM;
    float ss = 0.f;
    for (int j = threadIdx.x; j < DM; j += 256) { float v = xr[j]; ss += v*v; }
    #pragma unroll
    for (int off = 32; off > 0; off >>= 1) ss += __shfl_down(ss, off);
    __shared__ float red[4];
    int lane = threadIdx.x & 63, wv = threadIdx.x >> 6;
    if (lane == 0) red[wv] = ss;
    __syncthreads();
    if (threadIdx.x == 0) {
        float t = red[0] + red[1] + red[2] + red[3];
        red[0] = rsqrtf(t / (float)DM + 1e-5f);
    }
    __syncthreads();
    float r = red[0];
    for (int j = threadIdx.x; j < DM; j += 256)
        out[(size_t)b*DM + j] = xr[j] * w[j] * r;
}

extern "C" void kernel_launch(void* const* d_in, const int* in_sizes, int n_in,
                              void* d_out, int out_size, void* d_ws, size_t ws_size,
                              hipStream_t stream)
{
    const float* batch   = (const float*)d_in[0];
    const void*  mask    = d_in[1];
    const float* norm_w  = (const float*)d_in[2];
    const float* W_in    = (const float*)d_in[3];
    const float* conv_w  = (const float*)d_in[4];
    const float* conv_b  = (const float*)d_in[5];
    const float* W_x     = (const float*)d_in[6];
    const float* W_dt    = (const float*)d_in[7];
    const float* b_dt    = (const float*)d_in[8];
    const float* A_log   = (const float*)d_in[9];
    const float* D_skip  = (const float*)d_in[10];
    const float* W_out   = (const float*)d_in[11];
    const float* normf_w = (const float*)d_in[12];
    float* out = (float*)d_out;

    // ---------------- workspace layout ----------------
    float* ws   = (float*)d_ws;
    float* h    = ws;                            // NTOK*DM f32
    float* dbl  = h   + (size_t)NTOK*DM;         // NTOK*80 f32
    float* scr  = dbl + (size_t)NTOK*WXROWS;     // 3*SEG f32 (aliased scratch)
    const size_t SEG = (size_t)BB*NC*DI*DS;      // 3,145,728 elements
    float* dblp = scr;                           // [SKS][NTOK][80] f32 (dead before scanA)
    float* Cp4  = scr;                           // [SK4][NTOK][DM] f32 (written after scanC)
    // bf16 scan summaries alias the same region (3*SEG bf16 = first 1.5*SEG f32)
    __hip_bfloat16* Psum = (__hip_bfloat16*)scr;
    __hip_bfloat16* Hsum = Psum + SEG;
    __hip_bfloat16* Hin  = Hsum + SEG;
    __hip_bfloat16* xz_bf    = (__hip_bfloat16*)(scr + 3*SEG);
    __hip_bfloat16* xn_bf    = xz_bf + (size_t)NTOK*2*DI;
    __hip_bfloat16* u_bf     = xn_bf + (size_t)NTOK*DM;
    __hip_bfloat16* delta_bf = u_bf  + (size_t)NTOK*DI;
    __hip_bfloat16* y_bf     = delta_bf + (size_t)NTOK*DI;
    __hip_bfloat16* wbase    = y_bf + (size_t)NTOK*DI;

    const size_t WIN_L  = (size_t)2*DI*DM;
    const size_t WOUT_L = (size_t)DM*DI;
    const size_t WXP_L  = (size_t)128*DI;
    const size_t WSUM   = WIN_L + WOUT_L + WXP_L;

    size_t need_all = (size_t)((char*)(wbase + (size_t)NL*WSUM) - (char*)d_ws) + 256;
    const bool all = ws_size >= need_all;
    const int nlw = all ? NL : 1;

    __hip_bfloat16* Win_b  = wbase;
    __hip_bfloat16* Wout_b = Win_b  + (size_t)nlw*WIN_L;
    __hip_bfloat16* Wxp_b  = Wout_b + (size_t)nlw*WOUT_L;
    int* lengths = (int*)(Wxp_b + (size_t)nlw*WXP_L);

    transpose_in_kernel<<<dim3(LL/32, DM/32, BB), 256, 0, stream>>>(batch, h);
    lengths_kernel<<<1, 64, 0, stream>>>(mask, lengths);

    if (all) {
        cvt_bf16_kernel<<<(int)(NL*WIN_L/4/256), 256, 0, stream>>>(W_in, Win_b, (int)(NL*WIN_L));
        cvt_bf16_kernel<<<(int)(NL*WOUT_L/4/256), 256, 0, stream>>>(W_out, Wout_b, (int)(NL*WOUT_L));
        cvt_padrow_kernel<<<(int)(NL*WXP_L/4/256), 256, 0, stream>>>(
            W_x, Wxp_b, WXROWS, 128, DI, NL);
    }

    // layer-0 pre-norm
    rmsnorm_kernel<<<NTOK, 256, 0, stream>>>(h, norm_w, xn_bf);

    for (int i = 0; i < NL; ++i) {
        const float* cwi  = conv_w + (size_t)i * DI * DC;
        const float* cbi  = conv_b + (size_t)i * DI;
        const float* Wdti = W_dt  + (size_t)i * DI * DTR;
        const float* bdti = b_dt  + (size_t)i * DI;
        const float* Ali  = A_log + (size_t)i * DI * DS;
        const float* Dski = D_skip + (size_t)i * DI;

        if (!all) {
            cvt_bf16_kernel<<<(int)(WIN_L/4/256), 256, 0, stream>>>(
                W_in + (size_t)i*WIN_L, Win_b, (int)WIN_L);
            cvt_bf16_kernel<<<(int)(WOUT_L/4/256), 256, 0, stream>>>(
                W_out + (size_t)i*WOUT_L, Wout_b, (int)WOUT_L);
            cvt_padrow_kernel<<<(int)(WXP_L/4/256), 256, 0, stream>>>(
                W_x + (size_t)i*WXROWS*DI, Wxp_b, WXROWS, 128, DI, 1);
        }
        const __hip_bfloat16* Win_l  = Win_b  + (all ? (size_t)i*WIN_L  : 0);
        const __hip_bfloat16* Wout_l = Wout_b + (all ? (size_t)i*WOUT_L : 0);
        const __hip_bfloat16* Wxp_l  = Wxp_b  + (all ? (size_t)i*WXP_L  : 0);

        // 2) xz = xn @ W_in^T  (MFMA 64M-tile, bf16 out, swizzled; 768 blocks)
        gemm_mfma_kernel<<<(2*DI/128)*(NTOK/64), 256, 0, stream>>>(
            xn_bf, Win_l, xz_bf, 2*DI/128, NTOK, 2*DI, DM);
        // 3) vectorized causal conv + SiLU -> u_bf (1536 blocks)
        conv_silu_kernel<<<(NTOK*DI/8 + 255)/256, 256, 0, stream>>>(xz_bf, cwi, cbi, u_bf);
        // 4) dbl-partials = u @ W_x^T  (MFMA 64M-tile split-K; 256 blocks)
        gemm_mfma_skinny<<<dim3(SKS, NTOK/64), 256, 0, stream>>>(u_bf, Wxp_l, dblp);
        // 5) fused split-K reduce + delta (1536 blocks)
        reduce_delta_kernel<<<dim3(DI/256, NTOK/DTB), 256, 0, stream>>>(
            dblp, Wdti, bdti, dbl, delta_bf);
        // 6) chunk-parallel scan (bf16 summaries; phaseB LDS-staged, 384 blocks)
        scan_phaseA<<<dim3(DI/256, NC, BB), 256, 0, stream>>>(
            delta_bf, u_bf, dbl, Ali, Psum, Hsum);
        scan_phaseB<<<BB*DI*DS/RBLK, 256, 0, stream>>>(Psum, Hsum, Hin);
        scan_phaseC<<<dim3(DI/256, NC, BB), 256, 0, stream>>>(
            delta_bf, u_bf, dbl, xz_bf, Ali, Dski, Hin, y_bf);
        // 7) h += y @ W_out^T  (64M-tile split-K=3, 576 blocks) + fused reduce/residual/norm
        gemm_mfma_splitk4<<<SK4*(NTOK/64)*(DM/128), 256, 0, stream>>>(
            y_bf, Wout_l, Cp4);
        reduce_add_norm_kernel<<<NTOK, 256, 0, stream>>>(
            Cp4, h, (i < NL-1) ? (norm_w + (size_t)(i+1)*DM) : nullptr, xn_bf);
    }

    final_kernel<<<BB, 256, 0, stream>>>(h, normf_w, lengths, out);
}

// Round 17
// 1060.959 us; speedup vs baseline: 1.3084x; 1.0033x over previous
//
#include <hip/hip_runtime.h>
#include <hip/hip_bf16.h>
#include <math.h>

// Problem dims (fixed)
#define BB 2
#define LL 1024
#define DM 768
#define NL 8
#define DS 16
#define DC 4
#define DI 1536
#define DTR 48
#define NTOK (BB*LL)          // 2048
#define WXROWS (DTR + 2*DS)   // 80
#define NC 128                // scan chunks
#define CT (LL/NC)            // 8 timesteps per chunk
#define SKS 8                 // split-K for W_x GEMM
#define SKC (DI/SKS)          // 192 per split
#define SK4 3                 // split-K for W_out GEMM
#define SK4C (DI/SK4)         // 512 per split
#define DTB 8                 // tokens per delta-kernel block
#define RBLK 64               // r-values per phaseB block

typedef __attribute__((ext_vector_type(8))) short bf16x8;
typedef __attribute__((ext_vector_type(4))) float f32x4;

__device__ inline void gload_lds16(const void* g, void* l) {
    __builtin_amdgcn_global_load_lds(
        (const __attribute__((address_space(1))) unsigned int*)g,
        (__attribute__((address_space(3))) unsigned int*)l, 16, 0, 0);
}

// bijective XCD swizzle for nwg % 8 == 0
__device__ inline int xcd_swz(int orig, int nwg) {
    return (orig & 7) * (nwg >> 3) + (orig >> 3);
}

// ---------------- MFMA core: 64(M) x 128(N) tile, BK=64 per barrier period ----------------
// Barrier amortization: 6 gloads + ONE vmcnt(0)+barrier pair per 64-k step (was per 32-k).
__device__ inline void gemm_core64(
    const __hip_bfloat16* __restrict__ gA0,
    const __hip_bfloat16* __restrict__ gW0, const __hip_bfloat16* __restrict__ gW1,
    int kbeg, int kend, int w, int wr, int wc, int fr, int khi,
    f32x4 (&acc)[2][4])
{
    __shared__ short As[2][2048];
    __shared__ short Ws[2][4096];
    for (int k0 = kbeg; k0 < kend; k0 += 64) {
        gload_lds16(gA0 + k0,      &As[0][w*512]);
        gload_lds16(gA0 + k0 + 32, &As[1][w*512]);
        gload_lds16(gW0 + k0,      &Ws[0][w*512]);
        gload_lds16(gW0 + k0 + 32, &Ws[1][w*512]);
        gload_lds16(gW1 + k0,      &Ws[0][w*512 + 2048]);
        gload_lds16(gW1 + k0 + 32, &Ws[1][w*512 + 2048]);
        asm volatile("s_waitcnt vmcnt(0)" ::: "memory");
        __syncthreads();
        #pragma unroll
        for (int kk = 0; kk < 2; ++kk) {
            bf16x8 a4[2], b4[4];
            #pragma unroll
            for (int mi = 0; mi < 2; ++mi)
                a4[mi] = *(const bf16x8*)&As[kk][(wr*32 + mi*16 + fr)*32 + khi*8];
            #pragma unroll
            for (int ni = 0; ni < 4; ++ni)
                b4[ni] = *(const bf16x8*)&Ws[kk][(wc*64 + ni*16 + fr)*32 + khi*8];
            #pragma unroll
            for (int mi = 0; mi < 2; ++mi)
                #pragma unroll
                for (int ni = 0; ni < 4; ++ni)
                    acc[mi][ni] = __builtin_amdgcn_mfma_f32_16x16x32_bf16(
                        a4[mi], b4[ni], acc[mi][ni], 0, 0, 0);
        }
        __syncthreads();
    }
}

// ---------------- tiled input transpose: batch[b,d,l] -> h[b,l,d] ----------------
__global__ __launch_bounds__(256) void transpose_in_kernel(
    const float* __restrict__ batch, float* __restrict__ h)
{
    __shared__ float tile[32][33];
    const int b  = blockIdx.z;
    const int l0 = blockIdx.x * 32;
    const int d0 = blockIdx.y * 32;
    const int tx = threadIdx.x & 31;
    const int ty = threadIdx.x >> 5;          // 0..7
    #pragma unroll
    for (int i = ty; i < 32; i += 8)
        tile[i][tx] = batch[((size_t)b*DM + d0 + i)*LL + l0 + tx];
    __syncthreads();
    #pragma unroll
    for (int i = ty; i < 32; i += 8)
        h[((size_t)b*LL + l0 + i)*DM + d0 + tx] = tile[tx][i];
}

// ---------------- lengths from mask (robust to bool vs int32) ----------------
__global__ void lengths_kernel(const void* __restrict__ mask, int* __restrict__ lengths)
{
    int b = threadIdx.x;
    if (b >= BB) return;
    const unsigned int* mi = (const unsigned int*)mask;
    bool packed = (mi[0] == 0x01010101u);
    int cnt = 0;
    if (packed) {
        const unsigned char* mb = (const unsigned char*)mask;
        for (int i = 0; i < LL; ++i) cnt += (mb[(size_t)b*LL + i] != 0);
    } else {
        for (int i = 0; i < LL; ++i) cnt += (mi[(size_t)b*LL + i] != 0);
    }
    lengths[b] = cnt;
}

// ---------------- f32 -> bf16 conversions ----------------
__global__ __launch_bounds__(256) void cvt_bf16_kernel(
    const float* __restrict__ in, __hip_bfloat16* __restrict__ o, int n)
{
    int i = (blockIdx.x * 256 + threadIdx.x) * 4;
    if (i >= n) return;
    float4 v = *(const float4*)(in + i);
    __hip_bfloat16 h0 = __float2bfloat16(v.x);
    __hip_bfloat16 h1 = __float2bfloat16(v.y);
    __hip_bfloat16 h2 = __float2bfloat16(v.z);
    __hip_bfloat16 h3 = __float2bfloat16(v.w);
    ushort4 r;
    r.x = *(unsigned short*)&h0; r.y = *(unsigned short*)&h1;
    r.z = *(unsigned short*)&h2; r.w = *(unsigned short*)&h3;
    *(ushort4*)(o + i) = r;
}

__global__ __launch_bounds__(256) void cvt_padrow_kernel(
    const float* __restrict__ in, __hip_bfloat16* __restrict__ o,
    int nrin, int nrout, int ncol, int nmat)
{
    int i = (blockIdx.x * 256 + threadIdx.x) * 4;
    int tot = nmat * nrout * ncol;
    if (i >= tot) return;
    int m = i / (nrout * ncol);
    int rem = i - m * (nrout * ncol);
    int r = rem / ncol;
    int c = rem - r * ncol;
    ushort4 rr = {0,0,0,0};
    if (r < nrin) {
        float4 v = *(const float4*)(in + ((size_t)m*nrin + r)*ncol + c);
        __hip_bfloat16 h0 = __float2bfloat16(v.x);
        __hip_bfloat16 h1 = __float2bfloat16(v.y);
        __hip_bfloat16 h2 = __float2bfloat16(v.z);
        __hip_bfloat16 h3 = __float2bfloat16(v.w);
        rr.x = *(unsigned short*)&h0; rr.y = *(unsigned short*)&h1;
        rr.z = *(unsigned short*)&h2; rr.w = *(unsigned short*)&h3;
    }
    *(ushort4*)(o + i) = rr;
}

// ---------------- RMSNorm (per token, D=768) -> bf16 out ----------------
__global__ __launch_bounds__(256) void rmsnorm_kernel(
    const float* __restrict__ x, const float* __restrict__ w,
    __hip_bfloat16* __restrict__ o)
{
    int tok = blockIdx.x;
    const float* xr = x + (size_t)tok * DM;
    float ss = 0.f;
    for (int j = threadIdx.x; j < DM; j += 256) { float v = xr[j]; ss += v*v; }
    #pragma unroll
    for (int off = 32; off > 0; off >>= 1) ss += __shfl_down(ss, off);
    __shared__ float red[4];
    int lane = threadIdx.x & 63, wv = threadIdx.x >> 6;
    if (lane == 0) red[wv] = ss;
    __syncthreads();
    if (threadIdx.x == 0) {
        float t = red[0] + red[1] + red[2] + red[3];
        red[0] = rsqrtf(t / (float)DM + 1e-5f);
    }
    __syncthreads();
    float r = red[0];
    for (int j = threadIdx.x; j < DM; j += 256)
        o[(size_t)tok*DM + j] = __float2bfloat16(xr[j] * w[j] * r);
}

// ---------------- MFMA bf16 GEMM (full K, 64M x 128N tiles, swizzled): C = A @ W^T ----------------
__global__ __launch_bounds__(256) void gemm_mfma_kernel(
    const __hip_bfloat16* __restrict__ A,
    const __hip_bfloat16* __restrict__ W,
    __hip_bfloat16* __restrict__ C,
    int NT, int M, int N, int K)
{
    const int swz = xcd_swz(blockIdx.x, gridDim.x);
    const int bn = (swz % NT) * 128;
    const int bm = (swz / NT) * 64;
    const int t = threadIdx.x;
    const int w = t >> 6;
    const int lane = t & 63;
    const int wr = w >> 1, wc = w & 1;
    const int fr = lane & 15;
    const int khi = lane >> 4;

    f32x4 acc[2][4];
    #pragma unroll
    for (int mi = 0; mi < 2; ++mi)
        #pragma unroll
        for (int ni = 0; ni < 4; ++ni)
            acc[mi][ni] = (f32x4){0.f, 0.f, 0.f, 0.f};

    const int rowL = t >> 2;
    const int ks = (t & 3) * 8;
    gemm_core64(A + (size_t)(bm + rowL) * K + ks,
                W + (size_t)(bn + rowL) * K + ks,
                W + (size_t)(bn + 64 + rowL) * K + ks,
                0, K, w, wr, wc, fr, khi, acc);

    #pragma unroll
    for (int mi = 0; mi < 2; ++mi) {
        #pragma unroll
        for (int ni = 0; ni < 4; ++ni) {
            int gc = bn + wc*64 + ni*16 + fr;
            #pragma unroll
            for (int r = 0; r < 4; ++r) {
                int gr = bm + wr*32 + mi*16 + khi*4 + r;
                C[(size_t)gr * N + gc] = __float2bfloat16(acc[mi][ni][r]);
            }
        }
    }
}

// ---------------- W_out GEMM split-K=3, 64M tiles, swizzled 1D grid (576 blocks) ----------------
__global__ __launch_bounds__(256) void gemm_mfma_splitk4(
    const __hip_bfloat16* __restrict__ A,
    const __hip_bfloat16* __restrict__ W,
    float* __restrict__ Cp)
{
    const int swz = xcd_swz(blockIdx.x, gridDim.x);
    const int bm = (swz / 18) * 64;
    const int r18 = swz % 18;
    const int bn = (r18 % 6) * 128;
    const int split = r18 / 6;
    const int t = threadIdx.x;
    const int w = t >> 6;
    const int lane = t & 63;
    const int wr = w >> 1, wc = w & 1;
    const int fr = lane & 15;
    const int khi = lane >> 4;

    f32x4 acc[2][4];
    #pragma unroll
    for (int mi = 0; mi < 2; ++mi)
        #pragma unroll
        for (int ni = 0; ni < 4; ++ni)
            acc[mi][ni] = (f32x4){0.f, 0.f, 0.f, 0.f};

    const int rowL = t >> 2;
    const int ks = (t & 3) * 8;
    const int kbeg = split * SK4C;
    gemm_core64(A + (size_t)(bm + rowL) * DI + ks,
                W + (size_t)(bn + rowL) * DI + ks,
                W + (size_t)(bn + 64 + rowL) * DI + ks,
                kbeg, kbeg + SK4C, w, wr, wc, fr, khi, acc);

    #pragma unroll
    for (int mi = 0; mi < 2; ++mi) {
        #pragma unroll
        for (int ni = 0; ni < 4; ++ni) {
            int gc = bn + wc*64 + ni*16 + fr;
            #pragma unroll
            for (int r = 0; r < 4; ++r) {
                int gr = bm + wr*32 + mi*16 + khi*4 + r;
                Cp[((size_t)split*NTOK + gr)*DM + gc] = acc[mi][ni][r];
            }
        }
    }
}

// reduce split-K partials + residual add + next-layer RMSNorm (fused)
__global__ __launch_bounds__(256) void reduce_add_norm_kernel(
    const float* __restrict__ Cp, float* __restrict__ h,
    const float* __restrict__ nw, __hip_bfloat16* __restrict__ xn)
{
    int tok = blockIdx.x;
    int tid = threadIdx.x;
    float v[3];
    float ss = 0.f;
    #pragma unroll
    for (int r = 0; r < 3; ++r) {
        int j = tid + r*256;
        size_t o = (size_t)tok*DM + j;
        float x = h[o] + Cp[o] + Cp[(size_t)NTOK*DM + o] + Cp[2*(size_t)NTOK*DM + o];
        h[o] = x;
        v[r] = x;
        ss += x*x;
    }
    if (!nw) return;
    #pragma unroll
    for (int off = 32; off > 0; off >>= 1) ss += __shfl_down(ss, off);
    __shared__ float red[4];
    int lane = tid & 63, wv = tid >> 6;
    if (lane == 0) red[wv] = ss;
    __syncthreads();
    if (tid == 0) {
        float t = red[0] + red[1] + red[2] + red[3];
        red[0] = rsqrtf(t / (float)DM + 1e-5f);
    }
    __syncthreads();
    float rinv = red[0];
    #pragma unroll
    for (int r = 0; r < 3; ++r) {
        int j = tid + r*256;
        xn[(size_t)tok*DM + j] = __float2bfloat16(v[r] * nw[j] * rinv);
    }
}

// ---------------- skinny MFMA split-K GEMM (64M tiles): dblp[split][m][0..79] ----------------
__global__ __launch_bounds__(256) void gemm_mfma_skinny(
    const __hip_bfloat16* __restrict__ A,
    const __hip_bfloat16* __restrict__ W,
    float* __restrict__ Cp)
{
    const int split = blockIdx.x;
    const int bm = blockIdx.y * 64;
    const int t = threadIdx.x;
    const int w = t >> 6;
    const int lane = t & 63;
    const int wr = w >> 1, wc = w & 1;
    const int fr = lane & 15;
    const int khi = lane >> 4;

    f32x4 acc[2][4];
    #pragma unroll
    for (int mi = 0; mi < 2; ++mi)
        #pragma unroll
        for (int ni = 0; ni < 4; ++ni)
            acc[mi][ni] = (f32x4){0.f, 0.f, 0.f, 0.f};

    const int rowL = t >> 2;
    const int ks = (t & 3) * 8;
    const int kbeg = split * SKC;
    gemm_core64(A + (size_t)(bm + rowL) * DI + ks,
                W + (size_t)rowL * DI + ks,
                W + (size_t)(64 + rowL) * DI + ks,
                kbeg, kbeg + SKC, w, wr, wc, fr, khi, acc);

    #pragma unroll
    for (int mi = 0; mi < 2; ++mi) {
        #pragma unroll
        for (int ni = 0; ni < 4; ++ni) {
            int gc = wc*64 + ni*16 + fr;
            if (gc >= WXROWS) continue;
            #pragma unroll
            for (int r = 0; r < 4; ++r) {
                int gr = bm + wr*32 + mi*16 + khi*4 + r;
                Cp[((size_t)split*NTOK + gr)*WXROWS + gc] = acc[mi][ni][r];
            }
        }
    }
}

// ---------------- fused split-K reduce + delta ----------------
__global__ __launch_bounds__(256) void reduce_delta_kernel(
    const float* __restrict__ Cp,
    const float* __restrict__ W_dt, const float* __restrict__ b_dt,
    float* __restrict__ dbl, __hip_bfloat16* __restrict__ delta)
{
    __shared__ float ld[DTB*DTR];
    const int tid = threadIdx.x;
    const int d = blockIdx.x * 256 + tid;
    const int t0 = blockIdx.y * DTB;
    for (int j = tid; j < DTB*DTR; j += 256) {
        int tt = j / DTR, jj = j - tt*DTR;
        float s = 0.f;
        #pragma unroll
        for (int p = 0; p < SKS; ++p)
            s += Cp[((size_t)p*NTOK + t0 + tt)*WXROWS + jj];
        ld[j] = s;
    }
    if (blockIdx.x == 0) {
        for (int j = tid; j < DTB*WXROWS; j += 256) {
            int tt = j / WXROWS, jj = j - tt*WXROWS;
            float s = 0.f;
            #pragma unroll
            for (int p = 0; p < SKS; ++p)
                s += Cp[((size_t)p*NTOK + t0 + tt)*WXROWS + jj];
            dbl[(size_t)(t0 + tt)*WXROWS + jj] = s;
        }
    }
    float wdt[DTR];
    #pragma unroll
    for (int j = 0; j < DTR; j += 4) {
        float4 v = *(const float4*)(W_dt + (size_t)d*DTR + j);
        wdt[j] = v.x; wdt[j+1] = v.y; wdt[j+2] = v.z; wdt[j+3] = v.w;
    }
    const float bdt = b_dt[d];
    __syncthreads();
    #pragma unroll
    for (int tt = 0; tt < DTB; ++tt) {
        float dt = bdt;
        #pragma unroll
        for (int j = 0; j < DTR; ++j) dt = fmaf(ld[tt*DTR + j], wdt[j], dt);
        dt = (dt > 20.f) ? dt : log1pf(__expf(dt));
        delta[(size_t)(t0 + tt)*DI + d] = __float2bfloat16(dt);
    }
}

// ---------------- vectorized causal depthwise conv4 + bias + SiLU (8 ch/thread) ----------------
__global__ __launch_bounds__(256) void conv_silu_kernel(
    const __hip_bfloat16* __restrict__ xz, const float* __restrict__ cw,
    const float* __restrict__ cb, __hip_bfloat16* __restrict__ u)
{
    int idx = blockIdx.x * 256 + threadIdx.x;      // NTOK*DI/8 threads
    if (idx >= NTOK*DI/8) return;
    const int dg  = idx % (DI/8);
    const int row = idx / (DI/8);                   // b*LL + l
    const int l   = row % LL;
    const int d0  = dg * 8;

    float acc[8];
    {
        float4 c0 = *(const float4*)(cb + d0);
        float4 c1 = *(const float4*)(cb + d0 + 4);
        acc[0]=c0.x; acc[1]=c0.y; acc[2]=c0.z; acc[3]=c0.w;
        acc[4]=c1.x; acc[5]=c1.y; acc[6]=c1.z; acc[7]=c1.w;
    }
    float4 cwj[8];
    #pragma unroll
    for (int j = 0; j < 8; ++j)
        cwj[j] = *(const float4*)(cw + (size_t)(d0 + j)*4);

    #pragma unroll
    for (int k = 0; k < 4; ++k) {
        int ls = l - 3 + k;
        if (ls < 0) continue;
        bf16x8 v = *(const bf16x8*)(xz + (size_t)(row - 3 + k)*(2*DI) + d0);
        const __hip_bfloat16* vp = (const __hip_bfloat16*)&v;
        #pragma unroll
        for (int j = 0; j < 8; ++j) {
            float xv = __bfloat162float(vp[j]);
            float wv = (k == 0) ? cwj[j].x : (k == 1) ? cwj[j].y : (k == 2) ? cwj[j].z : cwj[j].w;
            acc[j] = fmaf(xv, wv, acc[j]);
        }
    }
    bf16x8 r;
    __hip_bfloat16* rp = (__hip_bfloat16*)&r;
    #pragma unroll
    for (int j = 0; j < 8; ++j) {
        float s = acc[j] / (1.f + __expf(-acc[j]));
        rp[j] = __float2bfloat16(s);
    }
    *(bf16x8*)(u + (size_t)row*DI + d0) = r;
}

// ================= chunk-parallel selective scan (bf16 summaries, NC=128) =================
__global__ __launch_bounds__(256) void scan_phaseA(
    const __hip_bfloat16* __restrict__ delta, const __hip_bfloat16* __restrict__ u,
    const float* __restrict__ dbl, const float* __restrict__ A_log,
    __hip_bfloat16* __restrict__ Psum, __hip_bfloat16* __restrict__ Hsum)
{
    const int d = blockIdx.x * 256 + threadIdx.x;
    const int c = blockIdx.y;
    const int b = blockIdx.z;
    float A[DS], P[DS], hl[DS];
    #pragma unroll
    for (int s = 0; s < DS; ++s) {
        A[s] = -expf(A_log[(size_t)d*DS + s]);
        P[s] = 1.f; hl[s] = 0.f;
    }
    const int t0 = c * CT;
    #pragma unroll
    for (int t = 0; t < CT; ++t) {
        const size_t row = (size_t)b*LL + t0 + t;
        const float* bc = dbl + row*WXROWS + DTR;
        float dt = __bfloat162float(delta[row*DI + d]);
        float du = dt * __bfloat162float(u[row*DI + d]);
        #pragma unroll
        for (int s = 0; s < DS; ++s) {
            float a = __expf(dt * A[s]);
            P[s] *= a;
            hl[s] = fmaf(a, hl[s], du * bc[s]);
        }
    }
    const size_t off = (((size_t)b*NC + c)*DI + d)*DS;
    #pragma unroll
    for (int s = 0; s < DS; ++s) {
        Psum[off+s] = __float2bfloat16(P[s]);
        Hsum[off+s] = __float2bfloat16(hl[s]);
    }
}

// LDS-staged phaseB (bf16 in/out): one block per (b, 64 consecutive r), NC=128.
__global__ __launch_bounds__(256) void scan_phaseB(
    const __hip_bfloat16* __restrict__ Psum, const __hip_bfloat16* __restrict__ Hsum,
    __hip_bfloat16* __restrict__ Hin)
{
    __shared__ float pA[NC][RBLK];   // 128*64*4 = 32 KB
    __shared__ float hA[NC][RBLK];   // 32 KB
    const int tid = threadIdx.x;
    const int blk = blockIdx.x;
    const int b = blk / (DI*DS/RBLK);
    const int r0 = (blk % (DI*DS/RBLK)) * RBLK;
    for (int j = tid; j < NC*RBLK; j += 256) {
        int c = j >> 6, rr = j & (RBLK-1);
        size_t off = ((size_t)(b*NC + c))*DI*DS + r0 + rr;
        pA[c][rr] = __bfloat162float(Psum[off]);
        hA[c][rr] = __bfloat162float(Hsum[off]);
    }
    __syncthreads();
    if (tid < RBLK) {
        float hc = 0.f;
        for (int c = 0; c < NC; ++c) {
            size_t off = ((size_t)(b*NC + c))*DI*DS + r0 + tid;
            Hin[off] = __float2bfloat16(hc);
            hc = fmaf(pA[c][tid], hc, hA[c][tid]);
        }
    }
}

__global__ __launch_bounds__(256) void scan_phaseC(
    const __hip_bfloat16* __restrict__ delta, const __hip_bfloat16* __restrict__ u,
    const float* __restrict__ dbl, const __hip_bfloat16* __restrict__ xz,
    const float* __restrict__ A_log, const float* __restrict__ Dsk,
    const __hip_bfloat16* __restrict__ Hin, __hip_bfloat16* __restrict__ yfull)
{
    const int d = blockIdx.x * 256 + threadIdx.x;
    const int c = blockIdx.y;
    const int b = blockIdx.z;
    float A[DS], h[DS];
    const size_t hoff = (((size_t)b*NC + c)*DI + d)*DS;
    #pragma unroll
    for (int s = 0; s < DS; ++s) {
        A[s] = -expf(A_log[(size_t)d*DS + s]);
        h[s] = __bfloat162float(Hin[hoff + s]);
    }
    const float dsk = Dsk[d];
    const int t0 = c * CT;
    #pragma unroll
    for (int t = 0; t < CT; ++t) {
        const size_t row = (size_t)b*LL + t0 + t;
        const float* bc = dbl + row*WXROWS + DTR;
        float dt = __bfloat162float(delta[row*DI + d]);
        float ut = __bfloat162float(u[row*DI + d]);
        float du = dt * ut;
        float y = 0.f;
        #pragma unroll
        for (int s = 0; s < DS; ++s) {
            float a = __expf(dt * A[s]);
            h[s] = fmaf(a, h[s], du * bc[s]);
            y = fmaf(h[s], bc[DS+s], y);
        }
        float zt = __bfloat162float(xz[row*(2*DI) + DI + d]);
        float sz = zt / (1.f + __expf(-zt));
        yfull[row*DI + d] = __float2bfloat16((y + ut * dsk) * sz);
    }
}

// ---------------- final rmsnorm + gather last valid token ----------------
__global__ __launch_bounds__(256) void final_kernel(
    const float* __restrict__ h, const float* __restrict__ w,
    const int* __restrict__ lengths, float* __restrict__ out)
{
    int b = blockIdx.x;
    int idx = lengths[b] - 1;
    const float* xr = h + ((size_t)b*LL + idx)*DM;
    float ss = 0.f;
    for (int j = threadIdx.x; j < DM; j += 256) { float v = xr[j]; ss += v*v; }
    #pragma unroll
    for (int off = 32; off > 0; off >>= 1) ss += __shfl_down(ss, off);
    __shared__ float red[4];
    int lane = threadIdx.x & 63, wv = threadIdx.x >> 6;
    if (lane == 0) red[wv] = ss;
    __syncthreads();
    if (threadIdx.x == 0) {
        float t = red[0] + red[1] + red[2] + red[3];
        red[0] = rsqrtf(t / (float)DM + 1e-5f);
    }
    __syncthreads();
    float r = red[0];
    for (int j = threadIdx.x; j < DM; j += 256)
        out[(size_t)b*DM + j] = xr[j] * w[j] * r;
}

extern "C" void kernel_launch(void* const* d_in, const int* in_sizes, int n_in,
                              void* d_out, int out_size, void* d_ws, size_t ws_size,
                              hipStream_t stream)
{
    const float* batch   = (const float*)d_in[0];
    const void*  mask    = d_in[1];
    const float* norm_w  = (const float*)d_in[2];
    const float* W_in    = (const float*)d_in[3];
    const float* conv_w  = (const float*)d_in[4];
    const float* conv_b  = (const float*)d_in[5];
    const float* W_x     = (const float*)d_in[6];
    const float* W_dt    = (const float*)d_in[7];
    const float* b_dt    = (const float*)d_in[8];
    const float* A_log   = (const float*)d_in[9];
    const float* D_skip  = (const float*)d_in[10];
    const float* W_out   = (const float*)d_in[11];
    const float* normf_w = (const float*)d_in[12];
    float* out = (float*)d_out;

    // ---------------- workspace layout ----------------
    float* ws   = (float*)d_ws;
    float* h    = ws;                            // NTOK*DM f32
    float* dbl  = h   + (size_t)NTOK*DM;         // NTOK*80 f32
    float* scr  = dbl + (size_t)NTOK*WXROWS;     // aliased scratch region
    const size_t SEGB = (size_t)BB*NC*DI*DS;     // 6,291,456 bf16 elements (NC=128)
    float* dblp = scr;                           // [SKS][NTOK][80] f32 (dead before scanA)
    float* Cp4  = scr;                           // [SK4][NTOK][DM] f32 (written after scanC)
    // bf16 scan summaries alias the same region: 3*SEGB bf16 = 3*SEGB/2 f32 = 9,437,184 f32
    __hip_bfloat16* Psum = (__hip_bfloat16*)scr;
    __hip_bfloat16* Hsum = Psum + SEGB;
    __hip_bfloat16* Hin  = Hsum + SEGB;
    __hip_bfloat16* xz_bf    = (__hip_bfloat16*)(scr + 3*SEGB/2);
    __hip_bfloat16* xn_bf    = xz_bf + (size_t)NTOK*2*DI;
    __hip_bfloat16* u_bf     = xn_bf + (size_t)NTOK*DM;
    __hip_bfloat16* delta_bf = u_bf  + (size_t)NTOK*DI;
    __hip_bfloat16* y_bf     = delta_bf + (size_t)NTOK*DI;
    __hip_bfloat16* wbase    = y_bf + (size_t)NTOK*DI;

    const size_t WIN_L  = (size_t)2*DI*DM;
    const size_t WOUT_L = (size_t)DM*DI;
    const size_t WXP_L  = (size_t)128*DI;
    const size_t WSUM   = WIN_L + WOUT_L + WXP_L;

    size_t need_all = (size_t)((char*)(wbase + (size_t)NL*WSUM) - (char*)d_ws) + 256;
    const bool all = ws_size >= need_all;
    const int nlw = all ? NL : 1;

    __hip_bfloat16* Win_b  = wbase;
    __hip_bfloat16* Wout_b = Win_b  + (size_t)nlw*WIN_L;
    __hip_bfloat16* Wxp_b  = Wout_b + (size_t)nlw*WOUT_L;
    int* lengths = (int*)(Wxp_b + (size_t)nlw*WXP_L);

    transpose_in_kernel<<<dim3(LL/32, DM/32, BB), 256, 0, stream>>>(batch, h);
    lengths_kernel<<<1, 64, 0, stream>>>(mask, lengths);

    if (all) {
        cvt_bf16_kernel<<<(int)(NL*WIN_L/4/256), 256, 0, stream>>>(W_in, Win_b, (int)(NL*WIN_L));
        cvt_bf16_kernel<<<(int)(NL*WOUT_L/4/256), 256, 0, stream>>>(W_out, Wout_b, (int)(NL*WOUT_L));
        cvt_padrow_kernel<<<(int)(NL*WXP_L/4/256), 256, 0, stream>>>(
            W_x, Wxp_b, WXROWS, 128, DI, NL);
    }

    // layer-0 pre-norm
    rmsnorm_kernel<<<NTOK, 256, 0, stream>>>(h, norm_w, xn_bf);

    for (int i = 0; i < NL; ++i) {
        const float* cwi  = conv_w + (size_t)i * DI * DC;
        const float* cbi  = conv_b + (size_t)i * DI;
        const float* Wdti = W_dt  + (size_t)i * DI * DTR;
        const float* bdti = b_dt  + (size_t)i * DI;
        const float* Ali  = A_log + (size_t)i * DI * DS;
        const float* Dski = D_skip + (size_t)i * DI;

        if (!all) {
            cvt_bf16_kernel<<<(int)(WIN_L/4/256), 256, 0, stream>>>(
                W_in + (size_t)i*WIN_L, Win_b, (int)WIN_L);
            cvt_bf16_kernel<<<(int)(WOUT_L/4/256), 256, 0, stream>>>(
                W_out + (size_t)i*WOUT_L, Wout_b, (int)WOUT_L);
            cvt_padrow_kernel<<<(int)(WXP_L/4/256), 256, 0, stream>>>(
                W_x + (size_t)i*WXROWS*DI, Wxp_b, WXROWS, 128, DI, 1);
        }
        const __hip_bfloat16* Win_l  = Win_b  + (all ? (size_t)i*WIN_L  : 0);
        const __hip_bfloat16* Wout_l = Wout_b + (all ? (size_t)i*WOUT_L : 0);
        const __hip_bfloat16* Wxp_l  = Wxp_b  + (all ? (size_t)i*WXP_L  : 0);

        // 2) xz = xn @ W_in^T  (MFMA 64M-tile, BK=64, bf16 out, swizzled; 768 blocks)
        gemm_mfma_kernel<<<(2*DI/128)*(NTOK/64), 256, 0, stream>>>(
            xn_bf, Win_l, xz_bf, 2*DI/128, NTOK, 2*DI, DM);
        // 3) vectorized causal conv + SiLU -> u_bf (1536 blocks)
        conv_silu_kernel<<<(NTOK*DI/8 + 255)/256, 256, 0, stream>>>(xz_bf, cwi, cbi, u_bf);
        // 4) dbl-partials = u @ W_x^T  (MFMA 64M-tile split-K; 256 blocks)
        gemm_mfma_skinny<<<dim3(SKS, NTOK/64), 256, 0, stream>>>(u_bf, Wxp_l, dblp);
        // 5) fused split-K reduce + delta (1536 blocks)
        reduce_delta_kernel<<<dim3(DI/256, NTOK/DTB), 256, 0, stream>>>(
            dblp, Wdti, bdti, dbl, delta_bf);
        // 6) chunk-parallel scan (NC=128; phaseB LDS-staged RBLK=64, 768 blocks)
        scan_phaseA<<<dim3(DI/256, NC, BB), 256, 0, stream>>>(
            delta_bf, u_bf, dbl, Ali, Psum, Hsum);
        scan_phaseB<<<BB*DI*DS/RBLK, 256, 0, stream>>>(Psum, Hsum, Hin);
        scan_phaseC<<<dim3(DI/256, NC, BB), 256, 0, stream>>>(
            delta_bf, u_bf, dbl, xz_bf, Ali, Dski, Hin, y_bf);
        // 7) h += y @ W_out^T  (64M-tile split-K=3, BK=64, 576 blocks) + fused reduce/residual/norm
        gemm_mfma_splitk4<<<SK4*(NTOK/64)*(DM/128), 256, 0, stream>>>(
            y_bf, Wout_l, Cp4);
        reduce_add_norm_kernel<<<NTOK, 256, 0, stream>>>(
            Cp4, h, (i < NL-1) ? (norm_w + (size_t)(i+1)*DM) : nullptr, xn_bf);
    }

    final_kernel<<<BB, 256, 0, stream>>>(h, normf_w, lengths, out);
}